// Round 1
// baseline (256.948 us; speedup 1.0000x reference)
//
#include <hip/hip_runtime.h>
#include <hip/hip_bf16.h>

// Sizes (compile-time)
#define SQ   1024      // S
#define BB   4         // B
#define DM   192       // D_MODEL
#define NH   12        // N_HEAD
#define DH   16        // D_HEAD
#define RL   2048      // RLEN
#define BN   (BB*NH)   // 48

// ---------- helpers ----------
__device__ __forceinline__ float bf_lo(unsigned u) { return __uint_as_float(u << 16); }
__device__ __forceinline__ float bf_hi(unsigned u) { return __uint_as_float(u & 0xffff0000u); }

__device__ __forceinline__ float dot8(uint4 u, const float* q, float a) {
    a = fmaf(bf_lo(u.x), q[0], a); a = fmaf(bf_hi(u.x), q[1], a);
    a = fmaf(bf_lo(u.y), q[2], a); a = fmaf(bf_hi(u.y), q[3], a);
    a = fmaf(bf_lo(u.z), q[4], a); a = fmaf(bf_hi(u.z), q[5], a);
    a = fmaf(bf_lo(u.w), q[6], a); a = fmaf(bf_hi(u.w), q[7], a);
    return a;
}
__device__ __forceinline__ void pv8(uint4 u, float p, float* acc) {
    acc[0] = fmaf(p, bf_lo(u.x), acc[0]); acc[1] = fmaf(p, bf_hi(u.x), acc[1]);
    acc[2] = fmaf(p, bf_lo(u.y), acc[2]); acc[3] = fmaf(p, bf_hi(u.y), acc[3]);
    acc[4] = fmaf(p, bf_lo(u.z), acc[4]); acc[5] = fmaf(p, bf_hi(u.z), acc[5]);
    acc[6] = fmaf(p, bf_lo(u.w), acc[6]); acc[7] = fmaf(p, bf_hi(u.w), acc[7]);
}
__device__ __forceinline__ float wave_max(float v) {
    #pragma unroll
    for (int o = 1; o < 64; o <<= 1) v = fmaxf(v, __shfl_xor(v, o));
    return v;
}
__device__ __forceinline__ float wave_sum(float v) {
    #pragma unroll
    for (int o = 1; o < 64; o <<= 1) v += __shfl_xor(v, o);
    return v;
}

// ---------- kernel 0: transpose Wo [192][192] -> WoT[t][h] ----------
__global__ __launch_bounds__(256) void k_transpose_wo(const float* __restrict__ Wo,
                                                      float* __restrict__ WoT) {
    int idx = blockIdx.x * 256 + threadIdx.x;   // 36864 total
    int h = idx / DM, u = idx % DM;
    WoT[u * DM + h] = Wo[idx];
}

// ---------- kernel 1: x projections (q+biases f32; k,v bf16) ----------
// grid 512, block 192. 8 rows per block to amortize weight reads.
__global__ __launch_bounds__(192) void k_proj_x(
    const float* __restrict__ x,
    const float* __restrict__ Wq, const float* __restrict__ Wk, const float* __restrict__ Wv,
    const float* __restrict__ rwb, const float* __restrict__ rrb,
    float* __restrict__ qw, float* __restrict__ qr,
    __hip_bfloat16* __restrict__ kh, __hip_bfloat16* __restrict__ vh)
{
    __shared__ float xs[8][DM];
    int t = threadIdx.x;
    int row0 = blockIdx.x * 8;
    #pragma unroll
    for (int rr = 0; rr < 8; ++rr) xs[rr][t] = x[(size_t)(row0 + rr) * DM + t];
    __syncthreads();
    float aq[8] = {0,0,0,0,0,0,0,0}, ak[8] = {0,0,0,0,0,0,0,0}, avv[8] = {0,0,0,0,0,0,0,0};
    for (int h = 0; h < DM; ++h) {
        float wq = Wq[h * DM + t], wk = Wk[h * DM + t], wv = Wv[h * DM + t];
        #pragma unroll
        for (int rr = 0; rr < 8; ++rr) {
            float xv = xs[rr][h];
            aq[rr] = fmaf(xv, wq, aq[rr]);
            ak[rr] = fmaf(xv, wk, ak[rr]);
            avv[rr] = fmaf(xv, wv, avv[rr]);
        }
    }
    int n = t >> 4, d = t & 15;
    float bw = rwb[t], br = rrb[t];
    #pragma unroll
    for (int rr = 0; rr < 8; ++rr) {
        int row = row0 + rr;
        int i = row >> 2, b = row & 3;                // row = i*B + b, B=4
        size_t o = ((size_t)(b * NH + n) * SQ + i) * DH + d;
        qw[o] = aq[rr] + bw;
        qr[o] = aq[rr] + br;
        kh[o] = __float2bfloat16(ak[rr]);
        vh[o] = __float2bfloat16(avv[rr]);
    }
}

// ---------- kernel 2: r projection (k_r bf16) ----------
// grid 1024, block 192.
__global__ __launch_bounds__(192) void k_proj_r(
    const float* __restrict__ r, const float* __restrict__ Wr,
    __hip_bfloat16* __restrict__ kr)
{
    __shared__ float rs[8][DM];
    int t = threadIdx.x;
    int row0 = blockIdx.x * 8;
    #pragma unroll
    for (int rr = 0; rr < 8; ++rr) rs[rr][t] = r[(size_t)(row0 + rr) * DM + t];
    __syncthreads();
    float a[8] = {0,0,0,0,0,0,0,0};
    for (int h = 0; h < DM; ++h) {
        float wr = Wr[h * DM + t];
        #pragma unroll
        for (int rr = 0; rr < 8; ++rr) a[rr] = fmaf(rs[rr][h], wr, a[rr]);
    }
    int n = t >> 4, d = t & 15;
    #pragma unroll
    for (int rr = 0; rr < 8; ++rr) {
        int row = row0 + rr;
        int j = row >> 2, b = row & 3;                // row = j*B + b
        kr[((size_t)(b * NH + n) * RL + j) * DH + d] = __float2bfloat16(a[rr]);
    }
}

// ---------- kernel 3: attention ----------
// One wave per query row; lanes parallel over keys (16 keys/lane held as
// registered scores -> no online-softmax rescale). grid 48*256, block 256.
__global__ __launch_bounds__(256) void k_attn(
    const float* __restrict__ qw, const float* __restrict__ qr,
    const unsigned short* __restrict__ kh, const unsigned short* __restrict__ vh,
    const unsigned short* __restrict__ kr, float* __restrict__ av)
{
    int bn = blockIdx.x >> 8;
    int tile = blockIdx.x & 255;
    int wid = threadIdx.x >> 6, lane = threadIdx.x & 63;
    int i = tile * 4 + wid;
    size_t bnS = (size_t)bn * SQ;
    const float* qwp = qw + (bnS + i) * DH;
    const float* qrp = qr + (bnS + i) * DH;
    float q1[DH], q2[DH];
    #pragma unroll
    for (int d = 0; d < DH; ++d) { q1[d] = qwp[d]; q2[d] = qrp[d]; }

    const uint4* kbase = (const uint4*)(kh + bnS * DH);                    // 2 uint4 per row
    const uint4* vbase = (const uint4*)(vh + bnS * DH);
    // shifted kr base: row m = j + (S - i); base points at row (S - i)
    const uint4* rbase = (const uint4*)(kr + ((size_t)bn * RL + (SQ - i)) * DH);

    float s[16];
    #pragma unroll
    for (int tt = 0; tt < 16; ++tt) {
        int j = tt * 64 + lane;
        uint4 ka = kbase[2 * j], kb = kbase[2 * j + 1];
        uint4 ra = rbase[2 * j], rb = rbase[2 * j + 1];
        float acc = 0.f;
        acc = dot8(ka, q1 + 0, acc); acc = dot8(kb, q1 + 8, acc);
        acc = dot8(ra, q2 + 0, acc); acc = dot8(rb, q2 + 8, acc);
        s[tt] = acc * 0.25f;   // 1/sqrt(16)
    }
    float M = s[0];
    #pragma unroll
    for (int tt = 1; tt < 16; ++tt) M = fmaxf(M, s[tt]);
    M = wave_max(M);

    float l = 0.f;
    float acc[DH];
    #pragma unroll
    for (int d = 0; d < DH; ++d) acc[d] = 0.f;
    #pragma unroll
    for (int tt = 0; tt < 16; ++tt) {
        int j = tt * 64 + lane;
        float p = __expf(s[tt] - M);
        l += p;
        uint4 va = vbase[2 * j], vb = vbase[2 * j + 1];
        pv8(va, p, acc + 0); pv8(vb, p, acc + 8);
    }
    l = wave_sum(l);
    #pragma unroll
    for (int d = 0; d < DH; ++d) acc[d] = wave_sum(acc[d]);
    if (lane < DH) av[(bnS + i) * DH + lane] = acc[lane] / l;
}

// ---------- kernel 4: output projection + residual + LayerNorm ----------
// grid 1024, block 192. 4 rows per block.
__global__ __launch_bounds__(192) void k_out_ln(
    const float* __restrict__ av, const float* __restrict__ WoT,
    const float* __restrict__ x,
    const float* __restrict__ lnw, const float* __restrict__ lnb,
    float* __restrict__ out)
{
    __shared__ float as_[4][DM];
    __shared__ float red[2][4][3];
    int t = threadIdx.x;
    int row0 = blockIdx.x * 4;
    int n = t >> 4, d = t & 15;
    #pragma unroll
    for (int rr = 0; rr < 4; ++rr) {
        int row = row0 + rr;
        int i = row >> 2, b = row & 3;
        as_[rr][t] = av[((size_t)(b * NH + n) * SQ + i) * DH + d];
    }
    __syncthreads();
    float o[4] = {0, 0, 0, 0};
    for (int u = 0; u < DM; ++u) {
        float w = WoT[u * DM + t];
        #pragma unroll
        for (int rr = 0; rr < 4; ++rr) o[rr] = fmaf(as_[rr][u], w, o[rr]);
    }
    #pragma unroll
    for (int rr = 0; rr < 4; ++rr) o[rr] += x[(size_t)(row0 + rr) * DM + t];

    int wv = t >> 6, lane = t & 63;
    #pragma unroll
    for (int rr = 0; rr < 4; ++rr) {
        float a = o[rr], b2 = a * a;
        #pragma unroll
        for (int off = 1; off < 64; off <<= 1) {
            a += __shfl_xor(a, off);
            b2 += __shfl_xor(b2, off);
        }
        if (lane == 0) { red[0][rr][wv] = a; red[1][rr][wv] = b2; }
    }
    __syncthreads();
    #pragma unroll
    for (int rr = 0; rr < 4; ++rr) {
        float sum = red[0][rr][0] + red[0][rr][1] + red[0][rr][2];
        float sq  = red[1][rr][0] + red[1][rr][1] + red[1][rr][2];
        float mean = sum * (1.0f / 192.0f);
        float var = sq * (1.0f / 192.0f) - mean * mean;
        float rstd = rsqrtf(var + 1e-12f);
        out[(size_t)(row0 + rr) * DM + t] = (o[rr] - mean) * rstd * lnw[t] + lnb[t];
    }
}

extern "C" void kernel_launch(void* const* d_in, const int* in_sizes, int n_in,
                              void* d_out, int out_size, void* d_ws, size_t ws_size,
                              hipStream_t stream) {
    const float* x   = (const float*)d_in[0];
    const float* r   = (const float*)d_in[1];
    // d_in[2] = mask0, zeroed by reference -> ignored
    const float* Wq  = (const float*)d_in[3];
    const float* Wk  = (const float*)d_in[4];
    const float* Wv  = (const float*)d_in[5];
    const float* Wo  = (const float*)d_in[6];
    const float* Wr  = (const float*)d_in[7];
    const float* rwb = (const float*)d_in[8];
    const float* rrb = (const float*)d_in[9];
    const float* lnw = (const float*)d_in[10];
    const float* lnb = (const float*)d_in[11];
    float* out = (float*)d_out;

    // workspace layout (bytes):
    // qw f32 [48][1024][16]   @ 0
    // qr f32                  @ 3145728
    // av f32                  @ 6291456
    // WoT f32 [192*192]       @ 9437184
    // kh bf16 [48][1024][16]  @ 9584640
    // vh bf16                 @ 11157504
    // kr bf16 [48][2048][16]  @ 12730368  (end 15876096 bytes)
    char* ws = (char*)d_ws;
    float* qw  = (float*)(ws + 0);
    float* qr  = (float*)(ws + 3145728);
    float* av  = (float*)(ws + 6291456);
    float* WoT = (float*)(ws + 9437184);
    __hip_bfloat16* kh = (__hip_bfloat16*)(ws + 9584640);
    __hip_bfloat16* vh = (__hip_bfloat16*)(ws + 11157504);
    __hip_bfloat16* kr = (__hip_bfloat16*)(ws + 12730368);

    k_transpose_wo<<<dim3(144), dim3(256), 0, stream>>>(Wo, WoT);
    k_proj_x<<<dim3(512), dim3(192), 0, stream>>>(x, Wq, Wk, Wv, rwb, rrb, qw, qr, kh, vh);
    k_proj_r<<<dim3(1024), dim3(192), 0, stream>>>(r, Wr, kr);
    k_attn<<<dim3(BN * 256), dim3(256), 0, stream>>>(qw, qr,
        (const unsigned short*)kh, (const unsigned short*)vh,
        (const unsigned short*)kr, av);
    k_out_ln<<<dim3(1024), dim3(192), 0, stream>>>(av, WoT, x, lnw, lnb, out);
}

// Round 3
// 142.785 us; speedup vs baseline: 1.7995x; 1.7995x over previous
//
#include <hip/hip_runtime.h>
#include <hip/hip_bf16.h>

// Sizes (compile-time)
#define SQ   1024      // S
#define BB   4         // B
#define DM   192       // D_MODEL
#define NH   12        // N_HEAD
#define DH   16        // D_HEAD
#define RL   2048      // RLEN
#define BN   (BB*NH)   // 48
#define NT   32        // key chunks of 32

typedef __attribute__((ext_vector_type(8))) short  short8;
typedef __attribute__((ext_vector_type(4))) float  f32x4;
typedef __attribute__((ext_vector_type(2))) unsigned u32x2;
typedef __attribute__((ext_vector_type(4))) unsigned u32x4;

__device__ __forceinline__ short f2bf(float f) {
    unsigned u = __float_as_uint(f);
    u += 0x7fff + ((u >> 16) & 1);
    return (short)(u >> 16);
}

// ---------- kernel 0: transpose Wo [192][192] -> WoT[t][h] ----------
__global__ __launch_bounds__(256) void k_transpose_wo(const float* __restrict__ Wo,
                                                      float* __restrict__ WoT) {
    int idx = blockIdx.x * 256 + threadIdx.x;   // 36864 total
    int h = idx / DM, u = idx % DM;
    WoT[u * DM + h] = Wo[idx];
}

// ---------- kernel 1: x projections (q+biases f32; k,v bf16), 16 rows/block ----------
__global__ __launch_bounds__(192) void k_proj_x(
    const float* __restrict__ x,
    const float* __restrict__ Wq, const float* __restrict__ Wk, const float* __restrict__ Wv,
    const float* __restrict__ rwb, const float* __restrict__ rrb,
    float* __restrict__ qw, float* __restrict__ qr,
    __hip_bfloat16* __restrict__ kh, __hip_bfloat16* __restrict__ vh)
{
    __shared__ __align__(16) float xs[16][DM];
    int t = threadIdx.x;
    int row0 = blockIdx.x * 16;
    #pragma unroll
    for (int rr = 0; rr < 16; ++rr) xs[rr][t] = x[(size_t)(row0 + rr) * DM + t];
    __syncthreads();
    float aq[16], ak[16], avv[16];
    #pragma unroll
    for (int rr = 0; rr < 16; ++rr) { aq[rr] = 0.f; ak[rr] = 0.f; avv[rr] = 0.f; }
    for (int h = 0; h < DM; h += 4) {
        float wq0 = Wq[(h+0)*DM + t], wq1 = Wq[(h+1)*DM + t], wq2 = Wq[(h+2)*DM + t], wq3 = Wq[(h+3)*DM + t];
        float wk0 = Wk[(h+0)*DM + t], wk1 = Wk[(h+1)*DM + t], wk2 = Wk[(h+2)*DM + t], wk3 = Wk[(h+3)*DM + t];
        float wv0 = Wv[(h+0)*DM + t], wv1 = Wv[(h+1)*DM + t], wv2 = Wv[(h+2)*DM + t], wv3 = Wv[(h+3)*DM + t];
        #pragma unroll
        for (int rr = 0; rr < 16; ++rr) {
            f32x4 xv = *(const f32x4*)(&xs[rr][h]);
            aq[rr] = fmaf(xv[0], wq0, aq[rr]); aq[rr] = fmaf(xv[1], wq1, aq[rr]);
            aq[rr] = fmaf(xv[2], wq2, aq[rr]); aq[rr] = fmaf(xv[3], wq3, aq[rr]);
            ak[rr] = fmaf(xv[0], wk0, ak[rr]); ak[rr] = fmaf(xv[1], wk1, ak[rr]);
            ak[rr] = fmaf(xv[2], wk2, ak[rr]); ak[rr] = fmaf(xv[3], wk3, ak[rr]);
            avv[rr] = fmaf(xv[0], wv0, avv[rr]); avv[rr] = fmaf(xv[1], wv1, avv[rr]);
            avv[rr] = fmaf(xv[2], wv2, avv[rr]); avv[rr] = fmaf(xv[3], wv3, avv[rr]);
        }
    }
    int n = t >> 4, d = t & 15;
    float bw = rwb[t], br = rrb[t];
    #pragma unroll
    for (int rr = 0; rr < 16; ++rr) {
        int row = row0 + rr;
        int i = row >> 2, b = row & 3;                // row = i*B + b, B=4
        size_t o = ((size_t)(b * NH + n) * SQ + i) * DH + d;
        qw[o] = aq[rr] + bw;
        qr[o] = aq[rr] + br;
        kh[o] = __float2bfloat16(ak[rr]);
        vh[o] = __float2bfloat16(avv[rr]);
    }
}

// ---------- kernel 2: r projection (k_r bf16), 16 rows/block ----------
__global__ __launch_bounds__(192) void k_proj_r(
    const float* __restrict__ r, const float* __restrict__ Wr,
    __hip_bfloat16* __restrict__ kr)
{
    __shared__ __align__(16) float rs[16][DM];
    int t = threadIdx.x;
    int row0 = blockIdx.x * 16;
    #pragma unroll
    for (int rr = 0; rr < 16; ++rr) rs[rr][t] = r[(size_t)(row0 + rr) * DM + t];
    __syncthreads();
    float a[16];
    #pragma unroll
    for (int rr = 0; rr < 16; ++rr) a[rr] = 0.f;
    for (int h = 0; h < DM; h += 4) {
        float w0 = Wr[(h+0)*DM + t], w1 = Wr[(h+1)*DM + t], w2 = Wr[(h+2)*DM + t], w3 = Wr[(h+3)*DM + t];
        #pragma unroll
        for (int rr = 0; rr < 16; ++rr) {
            f32x4 xv = *(const f32x4*)(&rs[rr][h]);
            a[rr] = fmaf(xv[0], w0, a[rr]); a[rr] = fmaf(xv[1], w1, a[rr]);
            a[rr] = fmaf(xv[2], w2, a[rr]); a[rr] = fmaf(xv[3], w3, a[rr]);
        }
    }
    int n = t >> 4, d = t & 15;
    #pragma unroll
    for (int rr = 0; rr < 16; ++rr) {
        int row = row0 + rr;
        int j = row >> 2, b = row & 3;                // row = j*B + b
        kr[((size_t)(b * NH + n) * RL + j) * DH + d] = __float2bfloat16(a[rr]);
    }
}

// ---------- kernel 3: MFMA flash attention with relative shift ----------
// Block: 4 waves, 64 queries of one (b,n) head. 32-key chunks, dbuf K/V,
// 128-row KR ring. All MFMAs are 16x16x32 bf16 (AC/BD zero-pad K 16->32).
__global__ __launch_bounds__(256, 4) void k_attn_mfma(
    const float* __restrict__ qw, const float* __restrict__ qr,
    const unsigned short* __restrict__ kh, const unsigned short* __restrict__ vh,
    const unsigned short* __restrict__ kr, float* __restrict__ av)
{
    __shared__ __align__(16) short kbuf[2][512];   // 32 rows x 16 bf16
    __shared__ __align__(16) short vbuf[2][512];
    __shared__ __align__(16) short rbuf[128*16];   // KR ring, slot = row & 127
    __shared__ __align__(16) float sls[4][16*36];  // per-wave S scratch [i][j] pad36
    __shared__ __align__(16) float bdls[4][48*20]; // per-wave BD scratch [c][i] pad20

    // XCD swizzle: 16 blocks of one head land on one XCD (768 % 8 == 0)
    int bid = blockIdx.x;
    int logical = (bid & 7) * 96 + (bid >> 3);
    int bn = logical >> 4;
    int i0b = (logical & 15) * 64;

    int tid = threadIdx.x;
    int w = tid >> 6, lane = tid & 63;
    int g = lane >> 4, mm = lane & 15;

    size_t headK = (size_t)bn * SQ * DH;   // elems
    size_t headR = (size_t)bn * RL * DH;

    // ---- Q fragments (A-layout: i = lane&15, k = 8g+e; zeros for g>=2) ----
    short8 qwf = {0,0,0,0,0,0,0,0}, qrf = {0,0,0,0,0,0,0,0};
    {
        int qrow = i0b + 16*w + mm;
        if (g < 2) {
            const float* qp = qw + headK + (size_t)qrow*DH + 8*g;
            const float* rp = qr + headK + (size_t)qrow*DH + 8*g;
            const float SCL = 0.3606737602222409f;  // 0.25 * log2(e)
            #pragma unroll
            for (int e = 0; e < 8; ++e) {
                qwf[e] = f2bf(qp[e] * SCL);
                qrf[e] = f2bf(rp[e] * SCL);
            }
        }
    }

    // ---- prologue staging: K0, V0, KR rows [M0c0, M0c0+96) ----
    int M0c0 = 960 - i0b;    // M0c(t) = 32t + 960 - i0b  (always in [0,2048-96])
    if (w == 0) {
        u32x4 a = *(const u32x4*)(kh + headK + lane*8);
        *(u32x4*)(&kbuf[0][lane*8]) = a;
    } else if (w == 1) {
        u32x4 a = *(const u32x4*)(vh + headK + lane*8);
        *(u32x4*)(&vbuf[0][lane*8]) = a;
    } else if (w == 2) {
        int s0r = M0c0, s1r = M0c0 + 32;
        u32x4 a = *(const u32x4*)(kr + headR + (size_t)s0r*DH + lane*8);
        u32x4 b = *(const u32x4*)(kr + headR + (size_t)s1r*DH + lane*8);
        *(u32x4*)(&rbuf[(s0r & 127)*16 + lane*8]) = a;
        *(u32x4*)(&rbuf[(s1r & 127)*16 + lane*8]) = b;
    } else {
        int s2r = M0c0 + 64;
        u32x4 a = *(const u32x4*)(kr + headR + (size_t)s2r*DH + lane*8);
        *(u32x4*)(&rbuf[(s2r & 127)*16 + lane*8]) = a;
    }
    __syncthreads();

    float L = 0.f;
    f32x4 opv = {0.f,0.f,0.f,0.f};
    float* sw_ = sls[w];
    float* bw_ = bdls[w];
    int cur = 0;

    for (int t = 0; t < NT; ++t) {
        int j0 = t * 32;
        // 1. issue next-chunk global loads into regs (T14 split)
        u32x4 stg = {0,0,0,0};
        bool do_stage = (t + 1 < NT);
        if (do_stage) {
            if (w == 0)      stg = *(const u32x4*)(kh + headK + (size_t)(j0+32)*DH + lane*8);
            else if (w == 1) stg = *(const u32x4*)(vh + headK + (size_t)(j0+32)*DH + lane*8);
            else if (w == 2) {
                int sr = 32*t + 1056 - i0b;   // new ring rows [M0c(t)+96, +32)
                stg = *(const u32x4*)(kr + headR + (size_t)sr*DH + lane*8);
            }
        }

        f32x4 z = {0.f,0.f,0.f,0.f};
        // 2. AC = Qw @ K^T  (B: col=lane&15=key, k=8g+e=d; clamp g>=2 to real rows)
        const short* kc = &kbuf[cur][0];
        short8 kb0 = *(const short8*)(kc + (mm*16      + (g & 1)*8));
        short8 kb1 = *(const short8*)(kc + ((16+mm)*16 + (g & 1)*8));
        f32x4 ac0 = __builtin_amdgcn_mfma_f32_16x16x32_bf16(qwf, kb0, z, 0, 0, 0);
        f32x4 ac1 = __builtin_amdgcn_mfma_f32_16x16x32_bf16(qwf, kb1, z, 0, 0, 0);

        // 3. BD band = Qr @ KR^T over local cols c in [0,48)
        //    global KR row = j0 + 1008 - i0b - 16w + c,  ring slot = row & 127
        int mgbase = j0 + 1008 - i0b - 16*w + mm;
        short8 rb0 = *(const short8*)(rbuf + ((mgbase     ) & 127)*16 + (g & 1)*8);
        short8 rb1 = *(const short8*)(rbuf + ((mgbase + 16) & 127)*16 + (g & 1)*8);
        short8 rb2 = *(const short8*)(rbuf + ((mgbase + 32) & 127)*16 + (g & 1)*8);
        f32x4 bd0 = __builtin_amdgcn_mfma_f32_16x16x32_bf16(qrf, rb0, z, 0, 0, 0);
        f32x4 bd1 = __builtin_amdgcn_mfma_f32_16x16x32_bf16(qrf, rb1, z, 0, 0, 0);
        f32x4 bd2 = __builtin_amdgcn_mfma_f32_16x16x32_bf16(qrf, rb2, z, 0, 0, 0);

        // 4. BD -> LDS transposed [c][i] (pad 20), b128 writes
        *(f32x4*)(bw_ + (mm      *20 + 4*g)) = bd0;
        *(f32x4*)(bw_ + ((16+mm) *20 + 4*g)) = bd1;
        *(f32x4*)(bw_ + ((32+mm) *20 + 4*g)) = bd2;
        // 5. S (AC) -> LDS [i][j] (pad 36), acc layout: i=4g+r, j=lane&15+16*tile
        #pragma unroll
        for (int r = 0; r < 4; ++r) {
            sw_[(4*g + r)*36 + mm]      = ac0[r];
            sw_[(4*g + r)*36 + 16 + mm] = ac1[r];
        }

        // 6. read in A-layout (i=lane&15, j=8g+e), add shifted BD, exp2
        f32x4 s0 = *(const f32x4*)(sw_ + mm*36 + 8*g);
        f32x4 s1 = *(const f32x4*)(sw_ + mm*36 + 8*g + 4);
        float p[8];
        #pragma unroll
        for (int e = 0; e < 8; ++e) {
            int c = 8*g + e + 16 - mm;               // in [1,47]
            float sv = ((e < 4) ? s0[e] : s1[e-4]) + bw_[c*20 + mm];
            p[e] = __builtin_amdgcn_exp2f(sv);
        }
        L += ((p[0]+p[1]) + (p[2]+p[3])) + ((p[4]+p[5]) + (p[6]+p[7]));
        short8 pf;
        #pragma unroll
        for (int e = 0; e < 8; ++e) pf[e] = f2bf(p[e]);

        // 7. V B-frag via hw transpose read (keys 8g+0..7 at d=lane&15)
        unsigned voff = (unsigned)(size_t)(&vbuf[cur][0])
                      + ((unsigned)(lane & 15) << 3) + ((unsigned)(lane >> 4) << 8);
        u32x2 t0, t1;
        asm volatile("ds_read_b64_tr_b16 %0, %2 offset:0\n\t"
                     "ds_read_b64_tr_b16 %1, %2 offset:128\n\t"
                     "s_waitcnt lgkmcnt(0)"
                     : "=&v"(t0), "=&v"(t1) : "v"(voff));
        __builtin_amdgcn_sched_barrier(0);
        union { unsigned u[4]; short8 s; } vbu;
        vbu.u[0] = t0[0]; vbu.u[1] = t0[1]; vbu.u[2] = t1[0]; vbu.u[3] = t1[1];
        opv = __builtin_amdgcn_mfma_f32_16x16x32_bf16(pf, vbu.s, opv, 0, 0, 0);

        // 8. write staged regs to LDS (compiler inserts vmcnt), barrier
        if (do_stage) {
            if (w == 0)      *(u32x4*)(&kbuf[cur^1][lane*8]) = stg;
            else if (w == 1) *(u32x4*)(&vbuf[cur^1][lane*8]) = stg;
            else if (w == 2) {
                int sr = 32*t + 1056 - i0b;
                *(u32x4*)(&rbuf[(sr & 127)*16 + lane*8]) = stg;
            }
        }
        __syncthreads();
        cur ^= 1;
    }

    // ---- epilogue: normalize and store ----
    #pragma unroll
    for (int off = 16; off < 64; off <<= 1) L += __shfl_xor(L, off);
    #pragma unroll
    for (int r = 0; r < 4; ++r) {
        float lr = __shfl(L, 4*g + r);     // L for row 4g+r (held at lane 4g+r)
        int row = i0b + 16*w + 4*g + r;
        av[headK + (size_t)row*DH + mm] = opv[r] / lr;
    }
}

// ---------- kernel 4: output projection + residual + LayerNorm, 16 rows/block ----------
__global__ __launch_bounds__(192) void k_out_ln(
    const float* __restrict__ av, const float* __restrict__ WoT,
    const float* __restrict__ x,
    const float* __restrict__ lnw, const float* __restrict__ lnb,
    float* __restrict__ out)
{
    __shared__ __align__(16) float as_[16][DM];
    __shared__ float red[2][16][3];
    int t = threadIdx.x;
    int row0 = blockIdx.x * 16;
    int n = t >> 4, d = t & 15;
    #pragma unroll
    for (int rr = 0; rr < 16; ++rr) {
        int row = row0 + rr;
        int i = row >> 2, b = row & 3;
        as_[rr][t] = av[((size_t)(b * NH + n) * SQ + i) * DH + d];
    }
    __syncthreads();
    float o[16];
    #pragma unroll
    for (int rr = 0; rr < 16; ++rr) o[rr] = 0.f;
    for (int u = 0; u < DM; u += 4) {
        float w0 = WoT[(u+0)*DM + t], w1 = WoT[(u+1)*DM + t], w2 = WoT[(u+2)*DM + t], w3 = WoT[(u+3)*DM + t];
        #pragma unroll
        for (int rr = 0; rr < 16; ++rr) {
            f32x4 xv = *(const f32x4*)(&as_[rr][u]);
            o[rr] = fmaf(xv[0], w0, o[rr]); o[rr] = fmaf(xv[1], w1, o[rr]);
            o[rr] = fmaf(xv[2], w2, o[rr]); o[rr] = fmaf(xv[3], w3, o[rr]);
        }
    }
    #pragma unroll
    for (int rr = 0; rr < 16; ++rr) o[rr] += x[(size_t)(row0 + rr) * DM + t];

    int wv = t >> 6, lane = t & 63;
    #pragma unroll
    for (int rr = 0; rr < 16; ++rr) {
        float a = o[rr], b2 = a * a;
        #pragma unroll
        for (int off = 1; off < 64; off <<= 1) {
            a  += __shfl_xor(a, off);
            b2 += __shfl_xor(b2, off);
        }
        if (lane == 0) { red[0][rr][wv] = a; red[1][rr][wv] = b2; }
    }
    __syncthreads();
    #pragma unroll
    for (int rr = 0; rr < 16; ++rr) {
        float sum = red[0][rr][0] + red[0][rr][1] + red[0][rr][2];
        float sq  = red[1][rr][0] + red[1][rr][1] + red[1][rr][2];
        float mean = sum * (1.0f / 192.0f);
        float var = sq * (1.0f / 192.0f) - mean * mean;
        float rstd = rsqrtf(var + 1e-12f);
        out[(size_t)(row0 + rr) * DM + t] = (o[rr] - mean) * rstd * lnw[t] + lnb[t];
    }
}

extern "C" void kernel_launch(void* const* d_in, const int* in_sizes, int n_in,
                              void* d_out, int out_size, void* d_ws, size_t ws_size,
                              hipStream_t stream) {
    const float* x   = (const float*)d_in[0];
    const float* r   = (const float*)d_in[1];
    // d_in[2] = mask0, zeroed by reference -> ignored
    const float* Wq  = (const float*)d_in[3];
    const float* Wk  = (const float*)d_in[4];
    const float* Wv  = (const float*)d_in[5];
    const float* Wo  = (const float*)d_in[6];
    const float* Wr  = (const float*)d_in[7];
    const float* rwb = (const float*)d_in[8];
    const float* rrb = (const float*)d_in[9];
    const float* lnw = (const float*)d_in[10];
    const float* lnb = (const float*)d_in[11];
    float* out = (float*)d_out;

    // workspace layout (bytes):
    // qw f32 [48][1024][16]   @ 0
    // qr f32                  @ 3145728
    // av f32                  @ 6291456
    // WoT f32 [192*192]       @ 9437184
    // kh bf16 [48][1024][16]  @ 9584640
    // vh bf16                 @ 11157504
    // kr bf16 [48][2048][16]  @ 12730368  (end 15876096 bytes)
    char* ws = (char*)d_ws;
    float* qw  = (float*)(ws + 0);
    float* qr  = (float*)(ws + 3145728);
    float* av  = (float*)(ws + 6291456);
    float* WoT = (float*)(ws + 9437184);
    __hip_bfloat16* kh = (__hip_bfloat16*)(ws + 9584640);
    __hip_bfloat16* vh = (__hip_bfloat16*)(ws + 11157504);
    __hip_bfloat16* kr = (__hip_bfloat16*)(ws + 12730368);

    k_transpose_wo<<<dim3(144), dim3(256), 0, stream>>>(Wo, WoT);
    k_proj_x<<<dim3(256), dim3(192), 0, stream>>>(x, Wq, Wk, Wv, rwb, rrb, qw, qr, kh, vh);
    k_proj_r<<<dim3(512), dim3(192), 0, stream>>>(r, Wr, kr);
    k_attn_mfma<<<dim3(768), dim3(256), 0, stream>>>(qw, qr,
        (const unsigned short*)kh, (const unsigned short*)vh,
        (const unsigned short*)kr, av);
    k_out_ln<<<dim3(256), dim3(192), 0, stream>>>(av, WoT, x, lnw, lnb, out);
}

// Round 4
// 100.783 us; speedup vs baseline: 2.5495x; 1.4168x over previous
//
#include <hip/hip_runtime.h>
#include <hip/hip_bf16.h>

// Sizes (compile-time)
#define SQ   1024      // S
#define BB   4         // B
#define DM   192       // D_MODEL
#define NH   12        // N_HEAD
#define DH   16        // D_HEAD
#define RL   2048      // RLEN
#define BN   (BB*NH)   // 48
#define NT   32        // key chunks of 32

typedef __attribute__((ext_vector_type(8))) short  short8;
typedef __attribute__((ext_vector_type(4))) float  f32x4;
typedef __attribute__((ext_vector_type(2))) unsigned u32x2;
typedef __attribute__((ext_vector_type(4))) unsigned u32x4;

__device__ __forceinline__ short f2bf(float f) {
    unsigned u = __float_as_uint(f);
    u += 0x7fff + ((u >> 16) & 1);
    return (short)(u >> 16);
}

// ---------- kernel 0: transpose Wo [192][192] -> WoT[t][h] ----------
__global__ __launch_bounds__(256) void k_transpose_wo(const float* __restrict__ Wo,
                                                      float* __restrict__ WoT) {
    int idx = blockIdx.x * 256 + threadIdx.x;   // 36864 total
    int h = idx / DM, u = idx % DM;
    WoT[u * DM + h] = Wo[idx];
}

// ---------- kernel 1: x projections (q+biases f32; k,v bf16), 4 rows/block ----------
// grid 1024: 4 blocks/CU = 12 waves/CU for latency hiding.
__global__ __launch_bounds__(192) void k_proj_x(
    const float* __restrict__ x,
    const float* __restrict__ Wq, const float* __restrict__ Wk, const float* __restrict__ Wv,
    const float* __restrict__ rwb, const float* __restrict__ rrb,
    float* __restrict__ qw, float* __restrict__ qr,
    __hip_bfloat16* __restrict__ kh, __hip_bfloat16* __restrict__ vh)
{
    __shared__ __align__(16) float xs[4][DM];
    int t = threadIdx.x;
    int row0 = blockIdx.x * 4;
    #pragma unroll
    for (int rr = 0; rr < 4; ++rr) xs[rr][t] = x[(size_t)(row0 + rr) * DM + t];
    __syncthreads();
    float aq[4], ak[4], avv[4];
    #pragma unroll
    for (int rr = 0; rr < 4; ++rr) { aq[rr] = 0.f; ak[rr] = 0.f; avv[rr] = 0.f; }
    for (int h = 0; h < DM; h += 4) {
        float wq0 = Wq[(h+0)*DM + t], wq1 = Wq[(h+1)*DM + t], wq2 = Wq[(h+2)*DM + t], wq3 = Wq[(h+3)*DM + t];
        float wk0 = Wk[(h+0)*DM + t], wk1 = Wk[(h+1)*DM + t], wk2 = Wk[(h+2)*DM + t], wk3 = Wk[(h+3)*DM + t];
        float wv0 = Wv[(h+0)*DM + t], wv1 = Wv[(h+1)*DM + t], wv2 = Wv[(h+2)*DM + t], wv3 = Wv[(h+3)*DM + t];
        #pragma unroll
        for (int rr = 0; rr < 4; ++rr) {
            f32x4 xv = *(const f32x4*)(&xs[rr][h]);
            aq[rr] = fmaf(xv[0], wq0, aq[rr]); aq[rr] = fmaf(xv[1], wq1, aq[rr]);
            aq[rr] = fmaf(xv[2], wq2, aq[rr]); aq[rr] = fmaf(xv[3], wq3, aq[rr]);
            ak[rr] = fmaf(xv[0], wk0, ak[rr]); ak[rr] = fmaf(xv[1], wk1, ak[rr]);
            ak[rr] = fmaf(xv[2], wk2, ak[rr]); ak[rr] = fmaf(xv[3], wk3, ak[rr]);
            avv[rr] = fmaf(xv[0], wv0, avv[rr]); avv[rr] = fmaf(xv[1], wv1, avv[rr]);
            avv[rr] = fmaf(xv[2], wv2, avv[rr]); avv[rr] = fmaf(xv[3], wv3, avv[rr]);
        }
    }
    int n = t >> 4, d = t & 15;
    float bw = rwb[t], br = rrb[t];
    #pragma unroll
    for (int rr = 0; rr < 4; ++rr) {
        int row = row0 + rr;
        int i = row >> 2, b = row & 3;                // row = i*B + b, B=4
        size_t o = ((size_t)(b * NH + n) * SQ + i) * DH + d;
        qw[o] = aq[rr] + bw;
        qr[o] = aq[rr] + br;
        kh[o] = __float2bfloat16(ak[rr]);
        vh[o] = __float2bfloat16(avv[rr]);
    }
}

// ---------- kernel 2: r projection (k_r bf16), 4 rows/block ----------
// grid 2048.
__global__ __launch_bounds__(192) void k_proj_r(
    const float* __restrict__ r, const float* __restrict__ Wr,
    __hip_bfloat16* __restrict__ kr)
{
    __shared__ __align__(16) float rs[4][DM];
    int t = threadIdx.x;
    int row0 = blockIdx.x * 4;
    #pragma unroll
    for (int rr = 0; rr < 4; ++rr) rs[rr][t] = r[(size_t)(row0 + rr) * DM + t];
    __syncthreads();
    float a[4];
    #pragma unroll
    for (int rr = 0; rr < 4; ++rr) a[rr] = 0.f;
    for (int h = 0; h < DM; h += 4) {
        float w0 = Wr[(h+0)*DM + t], w1 = Wr[(h+1)*DM + t], w2 = Wr[(h+2)*DM + t], w3 = Wr[(h+3)*DM + t];
        #pragma unroll
        for (int rr = 0; rr < 4; ++rr) {
            f32x4 xv = *(const f32x4*)(&rs[rr][h]);
            a[rr] = fmaf(xv[0], w0, a[rr]); a[rr] = fmaf(xv[1], w1, a[rr]);
            a[rr] = fmaf(xv[2], w2, a[rr]); a[rr] = fmaf(xv[3], w3, a[rr]);
        }
    }
    int n = t >> 4, d = t & 15;
    #pragma unroll
    for (int rr = 0; rr < 4; ++rr) {
        int row = row0 + rr;
        int j = row >> 2, b = row & 3;                // row = j*B + b
        kr[((size_t)(b * NH + n) * RL + j) * DH + d] = __float2bfloat16(a[rr]);
    }
}

// ---------- kernel 3: MFMA flash attention with relative shift ----------
// Block: 4 waves, 64 queries of one (b,n) head. 32-key chunks, dbuf K/V,
// 128-row KR ring. All MFMAs are 16x16x32 bf16 (AC/BD zero-pad K 16->32).
__global__ __launch_bounds__(256, 4) void k_attn_mfma(
    const float* __restrict__ qw, const float* __restrict__ qr,
    const unsigned short* __restrict__ kh, const unsigned short* __restrict__ vh,
    const unsigned short* __restrict__ kr, float* __restrict__ av)
{
    __shared__ __align__(16) short kbuf[2][512];   // 32 rows x 16 bf16
    __shared__ __align__(16) short vbuf[2][512];
    __shared__ __align__(16) short rbuf[128*16];   // KR ring, slot = row & 127
    __shared__ __align__(16) float sls[4][16*36];  // per-wave S scratch [i][j] pad36
    __shared__ __align__(16) float bdls[4][48*20]; // per-wave BD scratch [c][i] pad20

    // XCD swizzle: 16 blocks of one head land on one XCD (768 % 8 == 0)
    int bid = blockIdx.x;
    int logical = (bid & 7) * 96 + (bid >> 3);
    int bn = logical >> 4;
    int i0b = (logical & 15) * 64;

    int tid = threadIdx.x;
    int w = tid >> 6, lane = tid & 63;
    int g = lane >> 4, mm = lane & 15;

    size_t headK = (size_t)bn * SQ * DH;   // elems
    size_t headR = (size_t)bn * RL * DH;

    // ---- Q fragments (A-layout: i = lane&15, k = 8g+e; zeros for g>=2) ----
    short8 qwf = {0,0,0,0,0,0,0,0}, qrf = {0,0,0,0,0,0,0,0};
    {
        int qrow = i0b + 16*w + mm;
        if (g < 2) {
            const float* qp = qw + headK + (size_t)qrow*DH + 8*g;
            const float* rp = qr + headK + (size_t)qrow*DH + 8*g;
            const float SCL = 0.3606737602222409f;  // 0.25 * log2(e)
            #pragma unroll
            for (int e = 0; e < 8; ++e) {
                qwf[e] = f2bf(qp[e] * SCL);
                qrf[e] = f2bf(rp[e] * SCL);
            }
        }
    }

    // ---- prologue staging: K0, V0, KR rows [M0c0, M0c0+96) ----
    int M0c0 = 960 - i0b;    // M0c(t) = 32t + 960 - i0b  (always in [0,2048-96])
    if (w == 0) {
        u32x4 a = *(const u32x4*)(kh + headK + lane*8);
        *(u32x4*)(&kbuf[0][lane*8]) = a;
    } else if (w == 1) {
        u32x4 a = *(const u32x4*)(vh + headK + lane*8);
        *(u32x4*)(&vbuf[0][lane*8]) = a;
    } else if (w == 2) {
        int s0r = M0c0, s1r = M0c0 + 32;
        u32x4 a = *(const u32x4*)(kr + headR + (size_t)s0r*DH + lane*8);
        u32x4 b = *(const u32x4*)(kr + headR + (size_t)s1r*DH + lane*8);
        *(u32x4*)(&rbuf[(s0r & 127)*16 + lane*8]) = a;
        *(u32x4*)(&rbuf[(s1r & 127)*16 + lane*8]) = b;
    } else {
        int s2r = M0c0 + 64;
        u32x4 a = *(const u32x4*)(kr + headR + (size_t)s2r*DH + lane*8);
        *(u32x4*)(&rbuf[(s2r & 127)*16 + lane*8]) = a;
    }
    __syncthreads();

    float L = 0.f;
    f32x4 opv = {0.f,0.f,0.f,0.f};
    float* sw_ = sls[w];
    float* bw_ = bdls[w];
    int cur = 0;

    for (int t = 0; t < NT; ++t) {
        int j0 = t * 32;
        // 1. issue next-chunk global loads into regs (T14 split)
        u32x4 stg = {0,0,0,0};
        bool do_stage = (t + 1 < NT);
        if (do_stage) {
            if (w == 0)      stg = *(const u32x4*)(kh + headK + (size_t)(j0+32)*DH + lane*8);
            else if (w == 1) stg = *(const u32x4*)(vh + headK + (size_t)(j0+32)*DH + lane*8);
            else if (w == 2) {
                int sr = 32*t + 1056 - i0b;   // new ring rows [M0c(t)+96, +32)
                stg = *(const u32x4*)(kr + headR + (size_t)sr*DH + lane*8);
            }
        }

        f32x4 z = {0.f,0.f,0.f,0.f};
        // 2. AC = Qw @ K^T  (B: col=lane&15=key, k=8g+e=d; clamp g>=2 to real rows)
        const short* kc = &kbuf[cur][0];
        short8 kb0 = *(const short8*)(kc + (mm*16      + (g & 1)*8));
        short8 kb1 = *(const short8*)(kc + ((16+mm)*16 + (g & 1)*8));
        f32x4 ac0 = __builtin_amdgcn_mfma_f32_16x16x32_bf16(qwf, kb0, z, 0, 0, 0);
        f32x4 ac1 = __builtin_amdgcn_mfma_f32_16x16x32_bf16(qwf, kb1, z, 0, 0, 0);

        // 3. BD band = Qr @ KR^T over local cols c in [0,48)
        //    global KR row = j0 + 1008 - i0b - 16w + c,  ring slot = row & 127
        int mgbase = j0 + 1008 - i0b - 16*w + mm;
        short8 rb0 = *(const short8*)(rbuf + ((mgbase     ) & 127)*16 + (g & 1)*8);
        short8 rb1 = *(const short8*)(rbuf + ((mgbase + 16) & 127)*16 + (g & 1)*8);
        short8 rb2 = *(const short8*)(rbuf + ((mgbase + 32) & 127)*16 + (g & 1)*8);
        f32x4 bd0 = __builtin_amdgcn_mfma_f32_16x16x32_bf16(qrf, rb0, z, 0, 0, 0);
        f32x4 bd1 = __builtin_amdgcn_mfma_f32_16x16x32_bf16(qrf, rb1, z, 0, 0, 0);
        f32x4 bd2 = __builtin_amdgcn_mfma_f32_16x16x32_bf16(qrf, rb2, z, 0, 0, 0);

        // 4. BD -> LDS transposed [c][i] (pad 20), b128 writes
        *(f32x4*)(bw_ + (mm      *20 + 4*g)) = bd0;
        *(f32x4*)(bw_ + ((16+mm) *20 + 4*g)) = bd1;
        *(f32x4*)(bw_ + ((32+mm) *20 + 4*g)) = bd2;
        // 5. S (AC) -> LDS [i][j] (pad 36), acc layout: i=4g+r, j=lane&15+16*tile
        #pragma unroll
        for (int r = 0; r < 4; ++r) {
            sw_[(4*g + r)*36 + mm]      = ac0[r];
            sw_[(4*g + r)*36 + 16 + mm] = ac1[r];
        }

        // 6. read in A-layout (i=lane&15, j=8g+e), add shifted BD, exp2
        f32x4 s0 = *(const f32x4*)(sw_ + mm*36 + 8*g);
        f32x4 s1 = *(const f32x4*)(sw_ + mm*36 + 8*g + 4);
        float p[8];
        #pragma unroll
        for (int e = 0; e < 8; ++e) {
            int c = 8*g + e + 16 - mm;               // in [1,47]
            float sv = ((e < 4) ? s0[e] : s1[e-4]) + bw_[c*20 + mm];
            p[e] = __builtin_amdgcn_exp2f(sv);
        }
        L += ((p[0]+p[1]) + (p[2]+p[3])) + ((p[4]+p[5]) + (p[6]+p[7]));
        short8 pf;
        #pragma unroll
        for (int e = 0; e < 8; ++e) pf[e] = f2bf(p[e]);

        // 7. V B-frag via hw transpose read (keys 8g+0..7 at d=lane&15)
        unsigned voff = (unsigned)(size_t)(&vbuf[cur][0])
                      + ((unsigned)(lane & 15) << 3) + ((unsigned)(lane >> 4) << 8);
        u32x2 t0, t1;
        asm volatile("ds_read_b64_tr_b16 %0, %2 offset:0\n\t"
                     "ds_read_b64_tr_b16 %1, %2 offset:128\n\t"
                     "s_waitcnt lgkmcnt(0)"
                     : "=&v"(t0), "=&v"(t1) : "v"(voff));
        __builtin_amdgcn_sched_barrier(0);
        union { unsigned u[4]; short8 s; } vbu;
        vbu.u[0] = t0[0]; vbu.u[1] = t0[1]; vbu.u[2] = t1[0]; vbu.u[3] = t1[1];
        opv = __builtin_amdgcn_mfma_f32_16x16x32_bf16(pf, vbu.s, opv, 0, 0, 0);

        // 8. write staged regs to LDS (compiler inserts vmcnt), barrier
        if (do_stage) {
            if (w == 0)      *(u32x4*)(&kbuf[cur^1][lane*8]) = stg;
            else if (w == 1) *(u32x4*)(&vbuf[cur^1][lane*8]) = stg;
            else if (w == 2) {
                int sr = 32*t + 1056 - i0b;
                *(u32x4*)(&rbuf[(sr & 127)*16 + lane*8]) = stg;
            }
        }
        __syncthreads();
        cur ^= 1;
    }

    // ---- epilogue: normalize and store ----
    #pragma unroll
    for (int off = 16; off < 64; off <<= 1) L += __shfl_xor(L, off);
    #pragma unroll
    for (int r = 0; r < 4; ++r) {
        float lr = __shfl(L, 4*g + r);     // L for row 4g+r (held at lane 4g+r)
        int row = i0b + 16*w + 4*g + r;
        av[headK + (size_t)row*DH + mm] = opv[r] / lr;
    }
}

// ---------- kernel 4: output projection + residual + LayerNorm, 4 rows/block ----------
// grid 1024.
__global__ __launch_bounds__(192) void k_out_ln(
    const float* __restrict__ av, const float* __restrict__ WoT,
    const float* __restrict__ x,
    const float* __restrict__ lnw, const float* __restrict__ lnb,
    float* __restrict__ out)
{
    __shared__ __align__(16) float as_[4][DM];
    __shared__ float red[2][4][3];
    int t = threadIdx.x;
    int row0 = blockIdx.x * 4;
    int n = t >> 4, d = t & 15;
    #pragma unroll
    for (int rr = 0; rr < 4; ++rr) {
        int row = row0 + rr;
        int i = row >> 2, b = row & 3;
        as_[rr][t] = av[((size_t)(b * NH + n) * SQ + i) * DH + d];
    }
    __syncthreads();
    float o[4];
    #pragma unroll
    for (int rr = 0; rr < 4; ++rr) o[rr] = 0.f;
    for (int u = 0; u < DM; u += 4) {
        float w0 = WoT[(u+0)*DM + t], w1 = WoT[(u+1)*DM + t], w2 = WoT[(u+2)*DM + t], w3 = WoT[(u+3)*DM + t];
        #pragma unroll
        for (int rr = 0; rr < 4; ++rr) {
            f32x4 xv = *(const f32x4*)(&as_[rr][u]);
            o[rr] = fmaf(xv[0], w0, o[rr]); o[rr] = fmaf(xv[1], w1, o[rr]);
            o[rr] = fmaf(xv[2], w2, o[rr]); o[rr] = fmaf(xv[3], w3, o[rr]);
        }
    }
    #pragma unroll
    for (int rr = 0; rr < 4; ++rr) o[rr] += x[(size_t)(row0 + rr) * DM + t];

    int wv = t >> 6, lane = t & 63;
    #pragma unroll
    for (int rr = 0; rr < 4; ++rr) {
        float a = o[rr], b2 = a * a;
        #pragma unroll
        for (int off = 1; off < 64; off <<= 1) {
            a  += __shfl_xor(a, off);
            b2 += __shfl_xor(b2, off);
        }
        if (lane == 0) { red[0][rr][wv] = a; red[1][rr][wv] = b2; }
    }
    __syncthreads();
    #pragma unroll
    for (int rr = 0; rr < 4; ++rr) {
        float sum = red[0][rr][0] + red[0][rr][1] + red[0][rr][2];
        float sq  = red[1][rr][0] + red[1][rr][1] + red[1][rr][2];
        float mean = sum * (1.0f / 192.0f);
        float var = sq * (1.0f / 192.0f) - mean * mean;
        float rstd = rsqrtf(var + 1e-12f);
        out[(size_t)(row0 + rr) * DM + t] = (o[rr] - mean) * rstd * lnw[t] + lnb[t];
    }
}

extern "C" void kernel_launch(void* const* d_in, const int* in_sizes, int n_in,
                              void* d_out, int out_size, void* d_ws, size_t ws_size,
                              hipStream_t stream) {
    const float* x   = (const float*)d_in[0];
    const float* r   = (const float*)d_in[1];
    // d_in[2] = mask0, zeroed by reference -> ignored
    const float* Wq  = (const float*)d_in[3];
    const float* Wk  = (const float*)d_in[4];
    const float* Wv  = (const float*)d_in[5];
    const float* Wo  = (const float*)d_in[6];
    const float* Wr  = (const float*)d_in[7];
    const float* rwb = (const float*)d_in[8];
    const float* rrb = (const float*)d_in[9];
    const float* lnw = (const float*)d_in[10];
    const float* lnb = (const float*)d_in[11];
    float* out = (float*)d_out;

    // workspace layout (bytes):
    // qw f32 [48][1024][16]   @ 0
    // qr f32                  @ 3145728
    // av f32                  @ 6291456
    // WoT f32 [192*192]       @ 9437184
    // kh bf16 [48][1024][16]  @ 9584640
    // vh bf16                 @ 11157504
    // kr bf16 [48][2048][16]  @ 12730368  (end 15876096 bytes)
    char* ws = (char*)d_ws;
    float* qw  = (float*)(ws + 0);
    float* qr  = (float*)(ws + 3145728);
    float* av  = (float*)(ws + 6291456);
    float* WoT = (float*)(ws + 9437184);
    __hip_bfloat16* kh = (__hip_bfloat16*)(ws + 9584640);
    __hip_bfloat16* vh = (__hip_bfloat16*)(ws + 11157504);
    __hip_bfloat16* kr = (__hip_bfloat16*)(ws + 12730368);

    k_transpose_wo<<<dim3(144), dim3(256), 0, stream>>>(Wo, WoT);
    k_proj_x<<<dim3(1024), dim3(192), 0, stream>>>(x, Wq, Wk, Wv, rwb, rrb, qw, qr, kh, vh);
    k_proj_r<<<dim3(2048), dim3(192), 0, stream>>>(r, Wr, kr);
    k_attn_mfma<<<dim3(768), dim3(256), 0, stream>>>(qw, qr,
        (const unsigned short*)kh, (const unsigned short*)vh,
        (const unsigned short*)kr, av);
    k_out_ln<<<dim3(1024), dim3(192), 0, stream>>>(av, WoT, x, lnw, lnb, out);
}

// Round 5
// 82.079 us; speedup vs baseline: 3.1305x; 1.2279x over previous
//
#include <hip/hip_runtime.h>
#include <hip/hip_bf16.h>

// Sizes (compile-time)
#define SQ   1024      // S
#define BB   4         // B
#define DM   192       // D_MODEL
#define NH   12        // N_HEAD
#define DH   16        // D_HEAD
#define RL   2048      // RLEN
#define BN   (BB*NH)   // 48
#define NT   32        // key chunks of 32

typedef __attribute__((ext_vector_type(8))) short  short8;
typedef __attribute__((ext_vector_type(4))) float  f32x4;
typedef __attribute__((ext_vector_type(2))) unsigned u32x2;
typedef __attribute__((ext_vector_type(4))) unsigned u32x4;

__device__ __forceinline__ short f2bf(float f) {
    unsigned u = __float_as_uint(f);
    u += 0x7fff + ((u >> 16) & 1);
    return (short)(u >> 16);
}

// ---------- kernel P: bf16 conversions + weight transposes ----------
// segments (element idx): xb 786432 | rb 1572864 | WTq/WTk/WTv/WTr 36864 each | Wob 36864
__global__ __launch_bounds__(256) void k_prep(
    const float* __restrict__ x, const float* __restrict__ r,
    const float* __restrict__ Wq, const float* __restrict__ Wk,
    const float* __restrict__ Wv, const float* __restrict__ Wr,
    const float* __restrict__ Wo,
    unsigned short* __restrict__ xb, unsigned short* __restrict__ rb,
    unsigned short* __restrict__ WTq, unsigned short* __restrict__ WTk,
    unsigned short* __restrict__ WTv, unsigned short* __restrict__ WTr,
    unsigned short* __restrict__ Wob)
{
    int idx = blockIdx.x * 256 + threadIdx.x;
    if (idx < 786432) { xb[idx] = (unsigned short)f2bf(x[idx]); return; }
    idx -= 786432;
    if (idx < 1572864) { rb[idx] = (unsigned short)f2bf(r[idx]); return; }
    idx -= 1572864;
    if (idx < 36864) { int nd = idx / 192, h = idx % 192;
                       WTq[idx] = (unsigned short)f2bf(Wq[h*192 + nd]); return; }
    idx -= 36864;
    if (idx < 36864) { int nd = idx / 192, h = idx % 192;
                       WTk[idx] = (unsigned short)f2bf(Wk[h*192 + nd]); return; }
    idx -= 36864;
    if (idx < 36864) { int nd = idx / 192, h = idx % 192;
                       WTv[idx] = (unsigned short)f2bf(Wv[h*192 + nd]); return; }
    idx -= 36864;
    if (idx < 36864) { int nd = idx / 192, h = idx % 192;
                       WTr[idx] = (unsigned short)f2bf(Wr[h*192 + nd]); return; }
    idx -= 36864;
    if (idx < 36864) { Wob[idx] = (unsigned short)f2bf(Wo[idx]); return; }
}

// ---------- kernel 1: x projections via MFMA ----------
// grid 2304 = 256 row-tiles x 9 (3 weights x 3 col-chunks of 64). 4 waves/block,
// wave w owns col-tile c0 = sub*64 + w*16. A = xb[4096][192], B = WT[col][k].
__global__ __launch_bounds__(256) void k_gemm_x(
    const unsigned short* __restrict__ xb,
    const unsigned short* __restrict__ WTq, const unsigned short* __restrict__ WTk,
    const unsigned short* __restrict__ WTv,
    const float* __restrict__ rwb, const float* __restrict__ rrb,
    unsigned short* __restrict__ qwb, unsigned short* __restrict__ qrb,
    unsigned short* __restrict__ kh, unsigned short* __restrict__ vh)
{
    int bid = blockIdx.x;
    int rt = bid / 9, ch = bid % 9;
    int wsel = ch / 3, sub = ch % 3;
    int tid = threadIdx.x, w = tid >> 6, lane = tid & 63, g = lane >> 4, mm = lane & 15;
    int c0 = sub * 64 + w * 16;
    const unsigned short* WT = (wsel == 0) ? WTq : ((wsel == 1) ? WTk : WTv);
    const unsigned short* arow = xb + (size_t)(rt*16 + mm) * 192 + 8*g;
    const unsigned short* brow = WT + (size_t)(c0 + mm) * 192 + 8*g;
    f32x4 acc = {0.f, 0.f, 0.f, 0.f};
    #pragma unroll
    for (int kk = 0; kk < 6; ++kk) {
        short8 a = *(const short8*)(arow + kk*32);
        short8 b = *(const short8*)(brow + kk*32);
        acc = __builtin_amdgcn_mfma_f32_16x16x32_bf16(a, b, acc, 0, 0, 0);
    }
    int col = c0 + mm, n = col >> 4, d = col & 15;
    if (wsel == 0) {
        const float SCL = 0.3606737602222409f;   // 0.25 * log2(e)
        float bw = rwb[col], br = rrb[col];
        #pragma unroll
        for (int r = 0; r < 4; ++r) {
            int row = rt*16 + 4*g + r;
            int i = row >> 2, b2 = row & 3;
            size_t o = ((size_t)(b2*NH + n) * SQ + i) * DH + d;
            qwb[o] = (unsigned short)f2bf((acc[r] + bw) * SCL);
            qrb[o] = (unsigned short)f2bf((acc[r] + br) * SCL);
        }
    } else {
        unsigned short* dst = (wsel == 1) ? kh : vh;
        #pragma unroll
        for (int r = 0; r < 4; ++r) {
            int row = rt*16 + 4*g + r;
            int i = row >> 2, b2 = row & 3;
            size_t o = ((size_t)(b2*NH + n) * SQ + i) * DH + d;
            dst[o] = (unsigned short)f2bf(acc[r]);
        }
    }
}

// ---------- kernel 2: r projection via MFMA ----------
// grid 1536 = 512 row-tiles x 3 col-chunks.
__global__ __launch_bounds__(256) void k_gemm_r(
    const unsigned short* __restrict__ rb, const unsigned short* __restrict__ WTr,
    unsigned short* __restrict__ kr)
{
    int bid = blockIdx.x;
    int rt = bid / 3, sub = bid % 3;
    int tid = threadIdx.x, w = tid >> 6, lane = tid & 63, g = lane >> 4, mm = lane & 15;
    int c0 = sub * 64 + w * 16;
    const unsigned short* arow = rb + (size_t)(rt*16 + mm) * 192 + 8*g;
    const unsigned short* brow = WTr + (size_t)(c0 + mm) * 192 + 8*g;
    f32x4 acc = {0.f, 0.f, 0.f, 0.f};
    #pragma unroll
    for (int kk = 0; kk < 6; ++kk) {
        short8 a = *(const short8*)(arow + kk*32);
        short8 b = *(const short8*)(brow + kk*32);
        acc = __builtin_amdgcn_mfma_f32_16x16x32_bf16(a, b, acc, 0, 0, 0);
    }
    int col = c0 + mm, n = col >> 4, d = col & 15;
    #pragma unroll
    for (int r = 0; r < 4; ++r) {
        int row = rt*16 + 4*g + r;
        int j = row >> 2, b2 = row & 3;
        kr[((size_t)(b2*NH + n) * RL + j) * DH + d] = (unsigned short)f2bf(acc[r]);
    }
}

// ---------- kernel 3: MFMA flash attention with relative shift ----------
// Block: 4 waves, 64 queries of one (b,n) head. 32-key chunks, dbuf K/V,
// 128-row KR ring. All MFMAs are 16x16x32 bf16 (AC/BD zero-pad K 16->32).
__global__ __launch_bounds__(256, 4) void k_attn_mfma(
    const unsigned short* __restrict__ qwb, const unsigned short* __restrict__ qrb,
    const unsigned short* __restrict__ kh, const unsigned short* __restrict__ vh,
    const unsigned short* __restrict__ kr, unsigned short* __restrict__ av_b)
{
    __shared__ __align__(16) short kbuf[2][512];   // 32 rows x 16 bf16
    __shared__ __align__(16) short vbuf[2][512];
    __shared__ __align__(16) short rbuf[128*16];   // KR ring, slot = row & 127
    __shared__ __align__(16) float sls[4][16*36];  // per-wave S scratch [i][j] pad36
    __shared__ __align__(16) float bdls[4][48*20]; // per-wave BD scratch [c][i] pad20

    // XCD swizzle: 16 blocks of one head land on one XCD (768 % 8 == 0)
    int bid = blockIdx.x;
    int logical = (bid & 7) * 96 + (bid >> 3);
    int bn = logical >> 4;
    int i0b = (logical & 15) * 64;

    int tid = threadIdx.x;
    int w = tid >> 6, lane = tid & 63;
    int g = lane >> 4, mm = lane & 15;

    size_t headK = (size_t)bn * SQ * DH;   // elems
    size_t headR = (size_t)bn * RL * DH;

    // ---- Q fragments (A-layout: i = lane&15, k = 8g+e; zeros for g>=2) ----
    // qwb/qrb already have bias added and 0.25*log2(e) scale folded, bf16.
    short8 qwf = {0,0,0,0,0,0,0,0}, qrf = {0,0,0,0,0,0,0,0};
    {
        int qrow = i0b + 16*w + mm;
        if (g < 2) {
            qwf = *(const short8*)((const short*)qwb + headK + (size_t)qrow*DH + 8*g);
            qrf = *(const short8*)((const short*)qrb + headK + (size_t)qrow*DH + 8*g);
        }
    }

    // ---- prologue staging: K0, V0, KR rows [M0c0, M0c0+96) ----
    int M0c0 = 960 - i0b;    // M0c(t) = 32t + 960 - i0b  (always in [0,2048-96])
    if (w == 0) {
        u32x4 a = *(const u32x4*)(kh + headK + lane*8);
        *(u32x4*)(&kbuf[0][lane*8]) = a;
    } else if (w == 1) {
        u32x4 a = *(const u32x4*)(vh + headK + lane*8);
        *(u32x4*)(&vbuf[0][lane*8]) = a;
    } else if (w == 2) {
        int s0r = M0c0, s1r = M0c0 + 32;
        u32x4 a = *(const u32x4*)(kr + headR + (size_t)s0r*DH + lane*8);
        u32x4 b = *(const u32x4*)(kr + headR + (size_t)s1r*DH + lane*8);
        *(u32x4*)(&rbuf[(s0r & 127)*16 + lane*8]) = a;
        *(u32x4*)(&rbuf[(s1r & 127)*16 + lane*8]) = b;
    } else {
        int s2r = M0c0 + 64;
        u32x4 a = *(const u32x4*)(kr + headR + (size_t)s2r*DH + lane*8);
        *(u32x4*)(&rbuf[(s2r & 127)*16 + lane*8]) = a;
    }
    __syncthreads();

    float L = 0.f;
    f32x4 opv = {0.f,0.f,0.f,0.f};
    float* sw_ = sls[w];
    float* bw_ = bdls[w];
    int cur = 0;

    for (int t = 0; t < NT; ++t) {
        int j0 = t * 32;
        // 1. issue next-chunk global loads into regs (T14 split)
        u32x4 stg = {0,0,0,0};
        bool do_stage = (t + 1 < NT);
        if (do_stage) {
            if (w == 0)      stg = *(const u32x4*)(kh + headK + (size_t)(j0+32)*DH + lane*8);
            else if (w == 1) stg = *(const u32x4*)(vh + headK + (size_t)(j0+32)*DH + lane*8);
            else if (w == 2) {
                int sr = 32*t + 1056 - i0b;   // new ring rows [M0c(t)+96, +32)
                stg = *(const u32x4*)(kr + headR + (size_t)sr*DH + lane*8);
            }
        }

        f32x4 z = {0.f,0.f,0.f,0.f};
        // 2. AC = Qw @ K^T  (B: col=lane&15=key, k=8g+e=d; clamp g>=2 to real rows)
        const short* kc = &kbuf[cur][0];
        short8 kb0 = *(const short8*)(kc + (mm*16      + (g & 1)*8));
        short8 kb1 = *(const short8*)(kc + ((16+mm)*16 + (g & 1)*8));
        f32x4 ac0 = __builtin_amdgcn_mfma_f32_16x16x32_bf16(qwf, kb0, z, 0, 0, 0);
        f32x4 ac1 = __builtin_amdgcn_mfma_f32_16x16x32_bf16(qwf, kb1, z, 0, 0, 0);

        // 3. BD band = Qr @ KR^T over local cols c in [0,48)
        //    global KR row = j0 + 1008 - i0b - 16w + c,  ring slot = row & 127
        int mgbase = j0 + 1008 - i0b - 16*w + mm;
        short8 rb0 = *(const short8*)(rbuf + ((mgbase     ) & 127)*16 + (g & 1)*8);
        short8 rb1 = *(const short8*)(rbuf + ((mgbase + 16) & 127)*16 + (g & 1)*8);
        short8 rb2 = *(const short8*)(rbuf + ((mgbase + 32) & 127)*16 + (g & 1)*8);
        f32x4 bd0 = __builtin_amdgcn_mfma_f32_16x16x32_bf16(qrf, rb0, z, 0, 0, 0);
        f32x4 bd1 = __builtin_amdgcn_mfma_f32_16x16x32_bf16(qrf, rb1, z, 0, 0, 0);
        f32x4 bd2 = __builtin_amdgcn_mfma_f32_16x16x32_bf16(qrf, rb2, z, 0, 0, 0);

        // 4. BD -> LDS transposed [c][i] (pad 20), b128 writes
        *(f32x4*)(bw_ + (mm      *20 + 4*g)) = bd0;
        *(f32x4*)(bw_ + ((16+mm) *20 + 4*g)) = bd1;
        *(f32x4*)(bw_ + ((32+mm) *20 + 4*g)) = bd2;
        // 5. S (AC) -> LDS [i][j] (pad 36), acc layout: i=4g+r, j=lane&15+16*tile
        #pragma unroll
        for (int r = 0; r < 4; ++r) {
            sw_[(4*g + r)*36 + mm]      = ac0[r];
            sw_[(4*g + r)*36 + 16 + mm] = ac1[r];
        }

        // 6. read in A-layout (i=lane&15, j=8g+e), add shifted BD, exp2
        f32x4 s0 = *(const f32x4*)(sw_ + mm*36 + 8*g);
        f32x4 s1 = *(const f32x4*)(sw_ + mm*36 + 8*g + 4);
        float p[8];
        #pragma unroll
        for (int e = 0; e < 8; ++e) {
            int c = 8*g + e + 16 - mm;               // in [1,47]
            float sv = ((e < 4) ? s0[e] : s1[e-4]) + bw_[c*20 + mm];
            p[e] = __builtin_amdgcn_exp2f(sv);
        }
        L += ((p[0]+p[1]) + (p[2]+p[3])) + ((p[4]+p[5]) + (p[6]+p[7]));
        short8 pf;
        #pragma unroll
        for (int e = 0; e < 8; ++e) pf[e] = f2bf(p[e]);

        // 7. V B-frag via hw transpose read (keys 8g+0..7 at d=lane&15)
        unsigned voff = (unsigned)(size_t)(&vbuf[cur][0])
                      + ((unsigned)(lane & 15) << 3) + ((unsigned)(lane >> 4) << 8);
        u32x2 t0, t1;
        asm volatile("ds_read_b64_tr_b16 %0, %2 offset:0\n\t"
                     "ds_read_b64_tr_b16 %1, %2 offset:128\n\t"
                     "s_waitcnt lgkmcnt(0)"
                     : "=&v"(t0), "=&v"(t1) : "v"(voff));
        __builtin_amdgcn_sched_barrier(0);
        union { unsigned u[4]; short8 s; } vbu;
        vbu.u[0] = t0[0]; vbu.u[1] = t0[1]; vbu.u[2] = t1[0]; vbu.u[3] = t1[1];
        opv = __builtin_amdgcn_mfma_f32_16x16x32_bf16(pf, vbu.s, opv, 0, 0, 0);

        // 8. write staged regs to LDS (compiler inserts vmcnt), barrier
        if (do_stage) {
            if (w == 0)      *(u32x4*)(&kbuf[cur^1][lane*8]) = stg;
            else if (w == 1) *(u32x4*)(&vbuf[cur^1][lane*8]) = stg;
            else if (w == 2) {
                int sr = 32*t + 1056 - i0b;
                *(u32x4*)(&rbuf[(sr & 127)*16 + lane*8]) = stg;
            }
        }
        __syncthreads();
        cur ^= 1;
    }

    // ---- epilogue: normalize, store bf16 row-major [4096][192] for out-GEMM ----
    #pragma unroll
    for (int off = 16; off < 64; off <<= 1) L += __shfl_xor(L, off);
    int b2 = bn / NH, nn = bn % NH;
    #pragma unroll
    for (int r = 0; r < 4; ++r) {
        float lr = __shfl(L, 4*g + r);     // L for row 4g+r (held at lane 4g+r)
        int i = i0b + 16*w + 4*g + r;
        av_b[((size_t)i*4 + b2)*192 + nn*16 + mm] = (unsigned short)f2bf(opv[r] / lr);
    }
}

// ---------- kernel 4: output projection via MFMA + residual ----------
// grid 768 = 256 row-tiles x 3 col-chunks. ao = av_b @ Wo^T(nd) + x (f32).
__global__ __launch_bounds__(256) void k_gemm_o(
    const unsigned short* __restrict__ av_b, const unsigned short* __restrict__ Wob,
    const float* __restrict__ x, float* __restrict__ ao)
{
    int bid = blockIdx.x;
    int rt = bid / 3, sub = bid % 3;
    int tid = threadIdx.x, w = tid >> 6, lane = tid & 63, g = lane >> 4, mm = lane & 15;
    int c0 = sub * 64 + w * 16;
    const unsigned short* arow = av_b + (size_t)(rt*16 + mm) * 192 + 8*g;
    const unsigned short* brow = Wob + (size_t)(c0 + mm) * 192 + 8*g;
    f32x4 acc = {0.f, 0.f, 0.f, 0.f};
    #pragma unroll
    for (int kk = 0; kk < 6; ++kk) {
        short8 a = *(const short8*)(arow + kk*32);
        short8 b = *(const short8*)(brow + kk*32);
        acc = __builtin_amdgcn_mfma_f32_16x16x32_bf16(a, b, acc, 0, 0, 0);
    }
    int col = c0 + mm;
    #pragma unroll
    for (int r = 0; r < 4; ++r) {
        size_t o = (size_t)(rt*16 + 4*g + r) * 192 + col;
        ao[o] = acc[r] + x[o];
    }
}

// ---------- kernel 5: LayerNorm over rows of ao ----------
// grid 1024, 4 waves/block, one wave per row; lane handles cols l, l+64, l+128.
__global__ __launch_bounds__(256) void k_ln(
    const float* __restrict__ ao,
    const float* __restrict__ lnw, const float* __restrict__ lnb,
    float* __restrict__ out)
{
    int tid = threadIdx.x, w = tid >> 6, lane = tid & 63;
    int row = blockIdx.x * 4 + w;
    const float* ar = ao + (size_t)row * 192;
    float v0 = ar[lane], v1 = ar[lane + 64], v2 = ar[lane + 128];
    float s = v0 + v1 + v2;
    float q = v0*v0 + v1*v1 + v2*v2;
    #pragma unroll
    for (int off = 1; off < 64; off <<= 1) {
        s += __shfl_xor(s, off);
        q += __shfl_xor(q, off);
    }
    float mean = s * (1.0f / 192.0f);
    float var = q * (1.0f / 192.0f) - mean * mean;
    float rstd = rsqrtf(var + 1e-12f);
    float* orow = out + (size_t)row * 192;
    orow[lane]       = (v0 - mean) * rstd * lnw[lane]       + lnb[lane];
    orow[lane + 64]  = (v1 - mean) * rstd * lnw[lane + 64]  + lnb[lane + 64];
    orow[lane + 128] = (v2 - mean) * rstd * lnw[lane + 128] + lnb[lane + 128];
}

extern "C" void kernel_launch(void* const* d_in, const int* in_sizes, int n_in,
                              void* d_out, int out_size, void* d_ws, size_t ws_size,
                              hipStream_t stream) {
    const float* x   = (const float*)d_in[0];
    const float* r   = (const float*)d_in[1];
    // d_in[2] = mask0, zeroed by reference -> ignored
    const float* Wq  = (const float*)d_in[3];
    const float* Wk  = (const float*)d_in[4];
    const float* Wv  = (const float*)d_in[5];
    const float* Wo  = (const float*)d_in[6];
    const float* Wr  = (const float*)d_in[7];
    const float* rwb = (const float*)d_in[8];
    const float* rrb = (const float*)d_in[9];
    const float* lnw = (const float*)d_in[10];
    const float* lnb = (const float*)d_in[11];
    float* out = (float*)d_out;

    // workspace layout (bytes):
    char* ws = (char*)d_ws;
    unsigned short* qwb = (unsigned short*)(ws + 0);         // [48][1024][16] bf16
    unsigned short* qrb = (unsigned short*)(ws + 1572864);
    unsigned short* kh  = (unsigned short*)(ws + 3145728);
    unsigned short* vh  = (unsigned short*)(ws + 4718592);
    unsigned short* kr  = (unsigned short*)(ws + 6291456);   // [48][2048][16] bf16
    unsigned short* avb = (unsigned short*)(ws + 9437184);   // [4096][192] bf16
    unsigned short* xb  = (unsigned short*)(ws + 11010048);  // [4096][192] bf16
    unsigned short* rb  = (unsigned short*)(ws + 12582912);  // [8192][192] bf16
    unsigned short* WTq = (unsigned short*)(ws + 15728640);  // [192][192] bf16 (transposed)
    unsigned short* WTk = (unsigned short*)(ws + 15802368);
    unsigned short* WTv = (unsigned short*)(ws + 15876096);
    unsigned short* WTr = (unsigned short*)(ws + 15949824);
    unsigned short* Wob = (unsigned short*)(ws + 16023552);  // [192][192] bf16 (as stored)
    float*          ao  = (float*)(ws + 16097280);           // [4096][192] f32

    k_prep<<<dim3(9936), dim3(256), 0, stream>>>(x, r, Wq, Wk, Wv, Wr, Wo,
                                                 xb, rb, WTq, WTk, WTv, WTr, Wob);
    k_gemm_x<<<dim3(2304), dim3(256), 0, stream>>>(xb, WTq, WTk, WTv, rwb, rrb,
                                                   qwb, qrb, kh, vh);
    k_gemm_r<<<dim3(1536), dim3(256), 0, stream>>>(rb, WTr, kr);
    k_attn_mfma<<<dim3(768), dim3(256), 0, stream>>>(qwb, qrb, kh, vh, kr, avb);
    k_gemm_o<<<dim3(768), dim3(256), 0, stream>>>(avb, Wob, x, ao);
    k_ln<<<dim3(1024), dim3(256), 0, stream>>>(ao, lnw, lnb, out);
}

// Round 6
// 70.313 us; speedup vs baseline: 3.6544x; 1.1673x over previous
//
#include <hip/hip_runtime.h>
#include <hip/hip_bf16.h>

// Sizes (compile-time)
#define SQ   1024      // S
#define BB   4         // B
#define DM   192       // D_MODEL
#define NH   12        // N_HEAD
#define DH   16        // D_HEAD
#define RL   2048      // RLEN
#define BN   (BB*NH)   // 48

typedef __attribute__((ext_vector_type(8))) short  short8;
typedef __attribute__((ext_vector_type(4))) float  f32x4;
typedef __attribute__((ext_vector_type(2))) unsigned u32x2;
typedef __attribute__((ext_vector_type(4))) unsigned u32x4;

__device__ __forceinline__ short f2bf(float f) {
    unsigned u = __float_as_uint(f);
    u += 0x7fff + ((u >> 16) & 1);
    return (short)(u >> 16);
}
// pack two f32 -> one u32 of 2 bf16 (lo, hi); compiler emits cvt_pk
__device__ __forceinline__ unsigned pkbf(float lo, float hi) {
    union { __hip_bfloat162 h; unsigned u; } cv;
    cv.h = __float22bfloat162_rn(make_float2(lo, hi));
    return cv.u;
}
#define P32SWAP(a, b) asm volatile("v_permlane32_swap_b32 %0, %1" : "+v"(a), "+v"(b))
#define P16SWAP(a, b) asm volatile("v_permlane16_swap_b32 %0, %1" : "+v"(a), "+v"(b))

// ---------- kernel P: bf16 conversions + weight transposes ----------
__global__ __launch_bounds__(256) void k_prep(
    const float* __restrict__ x, const float* __restrict__ r,
    const float* __restrict__ Wq, const float* __restrict__ Wk,
    const float* __restrict__ Wv, const float* __restrict__ Wr,
    const float* __restrict__ Wo,
    unsigned short* __restrict__ xb, unsigned short* __restrict__ rb,
    unsigned short* __restrict__ WTq, unsigned short* __restrict__ WTk,
    unsigned short* __restrict__ WTv, unsigned short* __restrict__ WTr,
    unsigned short* __restrict__ Wob)
{
    int idx = blockIdx.x * 256 + threadIdx.x;
    if (idx < 786432) { xb[idx] = (unsigned short)f2bf(x[idx]); return; }
    idx -= 786432;
    if (idx < 1572864) { rb[idx] = (unsigned short)f2bf(r[idx]); return; }
    idx -= 1572864;
    if (idx < 36864) { int nd = idx / 192, h = idx % 192;
                       WTq[idx] = (unsigned short)f2bf(Wq[h*192 + nd]); return; }
    idx -= 36864;
    if (idx < 36864) { int nd = idx / 192, h = idx % 192;
                       WTk[idx] = (unsigned short)f2bf(Wk[h*192 + nd]); return; }
    idx -= 36864;
    if (idx < 36864) { int nd = idx / 192, h = idx % 192;
                       WTv[idx] = (unsigned short)f2bf(Wv[h*192 + nd]); return; }
    idx -= 36864;
    if (idx < 36864) { int nd = idx / 192, h = idx % 192;
                       WTr[idx] = (unsigned short)f2bf(Wr[h*192 + nd]); return; }
    idx -= 36864;
    if (idx < 36864) { Wob[idx] = (unsigned short)f2bf(Wo[idx]); return; }
}

// ---------- kernel 1: fused x- and r-projections via MFMA ----------
// bid < 2304: x-path (256 row-tiles x {Wq,Wk,Wv} x 3 col-chunks)
// else      : r-path (512 row-tiles x 3 col-chunks)
__global__ __launch_bounds__(256) void k_gemm_xr(
    const unsigned short* __restrict__ xb, const unsigned short* __restrict__ rbm,
    const unsigned short* __restrict__ WTq, const unsigned short* __restrict__ WTk,
    const unsigned short* __restrict__ WTv, const unsigned short* __restrict__ WTr,
    const float* __restrict__ rwb, const float* __restrict__ rrb,
    unsigned short* __restrict__ qwb, unsigned short* __restrict__ qrb,
    unsigned short* __restrict__ kh, unsigned short* __restrict__ vh,
    unsigned short* __restrict__ kr)
{
    int bid = blockIdx.x;
    int tid = threadIdx.x, w = tid >> 6, lane = tid & 63, g = lane >> 4, mm = lane & 15;
    if (bid < 2304) {
        int rt = bid / 9, ch = bid % 9;
        int wsel = ch / 3, sub = ch % 3;
        int c0 = sub * 64 + w * 16;
        const unsigned short* WT = (wsel == 0) ? WTq : ((wsel == 1) ? WTk : WTv);
        const unsigned short* arow = xb + (size_t)(rt*16 + mm) * 192 + 8*g;
        const unsigned short* brow = WT + (size_t)(c0 + mm) * 192 + 8*g;
        f32x4 acc = {0.f, 0.f, 0.f, 0.f};
        #pragma unroll
        for (int kk = 0; kk < 6; ++kk) {
            short8 a = *(const short8*)(arow + kk*32);
            short8 b = *(const short8*)(brow + kk*32);
            acc = __builtin_amdgcn_mfma_f32_16x16x32_bf16(a, b, acc, 0, 0, 0);
        }
        int col = c0 + mm, n = col >> 4, d = col & 15;
        if (wsel == 0) {
            const float SCL = 0.3606737602222409f;   // 0.25 * log2(e)
            float bw = rwb[col], br = rrb[col];
            #pragma unroll
            for (int r = 0; r < 4; ++r) {
                int row = rt*16 + 4*g + r;
                int i = row >> 2, b2 = row & 3;
                size_t o = ((size_t)(b2*NH + n) * SQ + i) * DH + d;
                qwb[o] = (unsigned short)f2bf((acc[r] + bw) * SCL);
                qrb[o] = (unsigned short)f2bf((acc[r] + br) * SCL);
            }
        } else {
            unsigned short* dst = (wsel == 1) ? kh : vh;
            #pragma unroll
            for (int r = 0; r < 4; ++r) {
                int row = rt*16 + 4*g + r;
                int i = row >> 2, b2 = row & 3;
                size_t o = ((size_t)(b2*NH + n) * SQ + i) * DH + d;
                dst[o] = (unsigned short)f2bf(acc[r]);
            }
        }
    } else {
        int bb = bid - 2304;
        int rt = bb / 3, sub = bb % 3;
        int c0 = sub * 64 + w * 16;
        const unsigned short* arow = rbm + (size_t)(rt*16 + mm) * 192 + 8*g;
        const unsigned short* brow = WTr + (size_t)(c0 + mm) * 192 + 8*g;
        f32x4 acc = {0.f, 0.f, 0.f, 0.f};
        #pragma unroll
        for (int kk = 0; kk < 6; ++kk) {
            short8 a = *(const short8*)(arow + kk*32);
            short8 b = *(const short8*)(brow + kk*32);
            acc = __builtin_amdgcn_mfma_f32_16x16x32_bf16(a, b, acc, 0, 0, 0);
        }
        int col = c0 + mm, n = col >> 4, d = col & 15;
        #pragma unroll
        for (int r = 0; r < 4; ++r) {
            int row = rt*16 + 4*g + r;
            int j = row >> 2, b2 = row & 3;
            kr[((size_t)(b2*NH + n) * RL + j) * DH + d] = (unsigned short)f2bf(acc[r]);
        }
    }
}

// ---------- kernel 2: swapped-layout MFMA flash attention with rel-shift ----------
// 4 waves / 64 queries of one head; KVBLK=64, 1 barrier per chunk.
// All MFMAs swapped: C[row=key/d][col=query]. P goes C-layout -> PV B-frag via
// cvt_pk + permlane16/32_swap (no S LDS round-trip). BD band private per wave,
// [c][q] stride-20 layout => all LDS ops <=2-way conflicts.
__global__ __launch_bounds__(256, 3) void k_attn_mfma(
    const unsigned short* __restrict__ qwb, const unsigned short* __restrict__ qrb,
    const unsigned short* __restrict__ kh, const unsigned short* __restrict__ vh,
    const unsigned short* __restrict__ kr, unsigned short* __restrict__ av_b)
{
    __shared__ __align__(16) short kbuf[2][64*16];   // 4KB (dbuf K)
    __shared__ __align__(16) short vbuf[2][64*16];   // 4KB (dbuf V)
    __shared__ __align__(16) short rbuf[256*16];     // 8KB KR ring, slot = row & 255
    __shared__ __align__(16) float bdls[4][80*20];   // 25.6KB per-wave BD band [c][q]

    int bid = blockIdx.x;
    int logical = (bid & 7) * 96 + (bid >> 3);  // XCD swizzle (768 % 8 == 0)
    int bn = logical >> 4;
    int i0b = (logical & 15) * 64;
    int tid = threadIdx.x, w = tid >> 6, lane = tid & 63;
    int g = lane >> 4, mm = lane & 15;
    size_t headK = (size_t)bn * SQ * DH;
    size_t headR = (size_t)bn * RL * DH;

    // Q fragments (B-operand: col=mm=query, k=8g+e; zero for g>=2)
    short8 qwf = {0,0,0,0,0,0,0,0}, qrf = {0,0,0,0,0,0,0,0};
    if (g < 2) {
        int qrow = i0b + 16*w + mm;
        qwf = *(const short8*)((const short*)qwb + headK + (size_t)qrow*DH + 8*g);
        qrf = *(const short8*)((const short*)qrb + headK + (size_t)qrow*DH + 8*g);
    }

    // ---- prologue staging: K0 (64 rows), V0 (64 rows), KR ring [960-i0b, +128) ----
    {
        int hh = tid & 1;
        if (tid < 128) {
            int rr2 = tid >> 1;
            *(u32x4*)(&kbuf[0][rr2*16 + hh*8]) =
                *(const u32x4*)(kh + headK + (size_t)rr2*16 + hh*8);
        } else {
            int rr2 = (tid - 128) >> 1;
            *(u32x4*)(&vbuf[0][rr2*16 + hh*8]) =
                *(const u32x4*)(vh + headK + (size_t)rr2*16 + hh*8);
        }
        int rr2 = tid >> 1;
        int m = 960 - i0b + rr2;
        *(u32x4*)(&rbuf[(m & 255)*16 + hh*8]) =
            *(const u32x4*)(kr + headR + (size_t)m*16 + hh*8);
    }
    __syncthreads();

    float Lacc = 0.f;
    f32x4 opv = {0.f,0.f,0.f,0.f};
    float* bw_ = &bdls[w][0];
    const int basew0 = 1008 - i0b - 16*w;   // per-wave band base (t=0)
    const f32x4 z = {0.f,0.f,0.f,0.f};

    for (int t = 0; t < 16; ++t) {
        int cur = t & 1;
        // 1. stage-issue: next chunk global loads into regs (T14)
        u32x4 sa = {0,0,0,0}, sb = {0,0,0,0};
        bool ds = (t < 15);
        if (ds) {
            if (w == 0) {
                const unsigned short* p = kh + headK + (size_t)(64*(t+1) + lane)*16;
                sa = *(const u32x4*)p; sb = *(const u32x4*)(p + 8);
            } else if (w == 1) {
                const unsigned short* p = vh + headK + (size_t)(64*(t+1) + lane)*16;
                sa = *(const u32x4*)p; sb = *(const u32x4*)(p + 8);
            } else if (w == 2) {
                int m = 1088 + 64*t - i0b + lane;
                const unsigned short* p = kr + headR + (size_t)m*16;
                sa = *(const u32x4*)p; sb = *(const u32x4*)(p + 8);
            }
        }

        // 2. BD band: 5 swapped MFMAs -> private LDS [c][q] (stride 20, 2-way)
        int mb = basew0 + 64*t;
        #pragma unroll
        for (int tau = 0; tau < 5; ++tau) {
            int mr = (mb + 16*tau + mm) & 255;
            short8 ra = *(const short8*)(rbuf + mr*16 + 8*(g & 1));
            f32x4 bd = __builtin_amdgcn_mfma_f32_16x16x32_bf16(ra, qrf, z, 0, 0, 0);
            #pragma unroll
            for (int r = 0; r < 4; ++r)
                bw_[(16*tau + 4*g + r)*20 + mm] = bd[r];
        }

        // 3. AC (swapped) + shifted-BD add + exp2, all in C-layout
        unsigned pk[8]; float Lc = 0.f;
        #pragma unroll
        for (int tp = 0; tp < 4; ++tp) {
            short8 ka = *(const short8*)(&kbuf[cur][(16*tp + mm)*16 + 8*(g & 1)]);
            f32x4 ac = __builtin_amdgcn_mfma_f32_16x16x32_bf16(ka, qwf, z, 0, 0, 0);
            float p0 = __builtin_amdgcn_exp2f(ac[0] + bw_[(16*tp + 4*g + 0 + 16 - mm)*20 + mm]);
            float p1 = __builtin_amdgcn_exp2f(ac[1] + bw_[(16*tp + 4*g + 1 + 16 - mm)*20 + mm]);
            float p2 = __builtin_amdgcn_exp2f(ac[2] + bw_[(16*tp + 4*g + 2 + 16 - mm)*20 + mm]);
            float p3 = __builtin_amdgcn_exp2f(ac[3] + bw_[(16*tp + 4*g + 3 + 16 - mm)*20 + mm]);
            Lc += (p0 + p1) + (p2 + p3);
            pk[2*tp]     = pkbf(p0, p1);
            pk[2*tp + 1] = pkbf(p2, p3);
        }
        Lacc += Lc;

        // 4. C-layout P -> PV B-frag via permlane swaps (in-register transpose)
        P32SWAP(pk[0], pk[2]); P16SWAP(pk[0], pk[2]);
        P32SWAP(pk[1], pk[3]); P16SWAP(pk[1], pk[3]);
        P32SWAP(pk[4], pk[6]); P16SWAP(pk[4], pk[6]);
        P32SWAP(pk[5], pk[7]); P16SWAP(pk[5], pk[7]);

        // 5. PV: V A-frags via hw transpose-read, 2 MFMAs (keys 0-31, 32-63)
        unsigned vb0 = (unsigned)(size_t)(&vbuf[cur][0])
                     + ((unsigned)mm << 3) + ((unsigned)g << 8);
        {
            u32x2 t0, t1;
            asm volatile("ds_read_b64_tr_b16 %0, %2 offset:0\n\t"
                         "ds_read_b64_tr_b16 %1, %2 offset:128\n\t"
                         "s_waitcnt lgkmcnt(0)"
                         : "=&v"(t0), "=&v"(t1) : "v"(vb0));
            __builtin_amdgcn_sched_barrier(0);
            union { unsigned u[4]; short8 s; } va, pb;
            va.u[0]=t0[0]; va.u[1]=t0[1]; va.u[2]=t1[0]; va.u[3]=t1[1];
            pb.u[0]=pk[0]; pb.u[1]=pk[1]; pb.u[2]=pk[2]; pb.u[3]=pk[3];
            opv = __builtin_amdgcn_mfma_f32_16x16x32_bf16(va.s, pb.s, opv, 0, 0, 0);
        }
        {
            u32x2 t0, t1;
            asm volatile("ds_read_b64_tr_b16 %0, %2 offset:0\n\t"
                         "ds_read_b64_tr_b16 %1, %2 offset:128\n\t"
                         "s_waitcnt lgkmcnt(0)"
                         : "=&v"(t0), "=&v"(t1) : "v"(vb0 + 1024));
            __builtin_amdgcn_sched_barrier(0);
            union { unsigned u[4]; short8 s; } va, pb;
            va.u[0]=t0[0]; va.u[1]=t0[1]; va.u[2]=t1[0]; va.u[3]=t1[1];
            pb.u[0]=pk[4]; pb.u[1]=pk[5]; pb.u[2]=pk[6]; pb.u[3]=pk[7];
            opv = __builtin_amdgcn_mfma_f32_16x16x32_bf16(va.s, pb.s, opv, 0, 0, 0);
        }

        // 6. stage-write (disjoint LDS regions) + single barrier
        if (ds) {
            if (w == 0) {
                *(u32x4*)(&kbuf[cur^1][lane*16])     = sa;
                *(u32x4*)(&kbuf[cur^1][lane*16 + 8]) = sb;
            } else if (w == 1) {
                *(u32x4*)(&vbuf[cur^1][lane*16])     = sa;
                *(u32x4*)(&vbuf[cur^1][lane*16 + 8]) = sb;
            } else if (w == 2) {
                int ms = (1088 + 64*t - i0b + lane) & 255;
                *(u32x4*)(&rbuf[ms*16])     = sa;
                *(u32x4*)(&rbuf[ms*16 + 8]) = sb;
            }
        }
        __syncthreads();
    }

    // ---- epilogue: L is lane-local per query; reduce across g, store bf16 ----
    Lacc += __shfl_xor(Lacc, 16);
    Lacc += __shfl_xor(Lacc, 32);
    float inv = 1.0f / Lacc;
    int b2 = bn / NH, nn = bn % NH;
    int i = i0b + 16*w + mm;
    unsigned o0 = pkbf(opv[0]*inv, opv[1]*inv);
    unsigned o1 = pkbf(opv[2]*inv, opv[3]*inv);
    u32x2 ov = {o0, o1};
    *(u32x2*)(av_b + ((size_t)i*4 + b2)*192 + nn*16 + 4*g) = ov;
}

// ---------- kernel 3: output projection + residual + LayerNorm (fused) ----------
// grid 256: block computes 16 rows x all 192 cols (wave w -> col-tiles w*48+{0,16,32}),
// stores to LDS, then LN in-block (16 rows x 16 threads each).
__global__ __launch_bounds__(256) void k_out_ln(
    const unsigned short* __restrict__ avb, const unsigned short* __restrict__ Wob,
    const float* __restrict__ x,
    const float* __restrict__ lnw, const float* __restrict__ lnb,
    float* __restrict__ out)
{
    __shared__ __align__(16) float os[16][196];
    int tid = threadIdx.x, w = tid >> 6, lane = tid & 63, g = lane >> 4, mm = lane & 15;
    int rt = blockIdx.x;
    const unsigned short* arow = avb + (size_t)(rt*16 + mm)*192 + 8*g;
    short8 a[6];
    #pragma unroll
    for (int kk = 0; kk < 6; ++kk) a[kk] = *(const short8*)(arow + kk*32);
    #pragma unroll
    for (int s = 0; s < 3; ++s) {
        int c0 = w*48 + s*16;
        const unsigned short* brow = Wob + (size_t)(c0 + mm)*192 + 8*g;
        f32x4 acc = {0.f,0.f,0.f,0.f};
        #pragma unroll
        for (int kk = 0; kk < 6; ++kk) {
            short8 b = *(const short8*)(brow + kk*32);
            acc = __builtin_amdgcn_mfma_f32_16x16x32_bf16(a[kk], b, acc, 0, 0, 0);
        }
        int col = c0 + mm;
        #pragma unroll
        for (int r = 0; r < 4; ++r) {
            int rl = 4*g + r;
            os[rl][col] = acc[r] + x[(size_t)(rt*16 + rl)*192 + col];
        }
    }
    __syncthreads();
    int row = tid >> 4, seg = tid & 15;
    const float* ors = &os[row][0] + seg*12;
    f32x4 v0 = *(const f32x4*)(ors);
    f32x4 v1 = *(const f32x4*)(ors + 4);
    f32x4 v2 = *(const f32x4*)(ors + 8);
    float s1 = ((v0[0]+v0[1])+(v0[2]+v0[3])) + ((v1[0]+v1[1])+(v1[2]+v1[3]))
             + ((v2[0]+v2[1])+(v2[2]+v2[3]));
    float q1 = ((v0[0]*v0[0]+v0[1]*v0[1])+(v0[2]*v0[2]+v0[3]*v0[3]))
             + ((v1[0]*v1[0]+v1[1]*v1[1])+(v1[2]*v1[2]+v1[3]*v1[3]))
             + ((v2[0]*v2[0]+v2[1]*v2[1])+(v2[2]*v2[2]+v2[3]*v2[3]));
    #pragma unroll
    for (int off = 1; off < 16; off <<= 1) {
        s1 += __shfl_xor(s1, off);
        q1 += __shfl_xor(q1, off);
    }
    float mean = s1 * (1.0f / 192.0f);
    float var  = q1 * (1.0f / 192.0f) - mean * mean;
    float rstd = rsqrtf(var + 1e-12f);
    int c0 = seg * 12;
    size_t ro = (size_t)(rt*16 + row) * 192;
    #pragma unroll
    for (int c = 0; c < 12; ++c) {
        float v = (c < 4) ? v0[c] : ((c < 8) ? v1[c-4] : v2[c-8]);
        out[ro + c0 + c] = (v - mean) * rstd * lnw[c0 + c] + lnb[c0 + c];
    }
}

extern "C" void kernel_launch(void* const* d_in, const int* in_sizes, int n_in,
                              void* d_out, int out_size, void* d_ws, size_t ws_size,
                              hipStream_t stream) {
    const float* x   = (const float*)d_in[0];
    const float* r   = (const float*)d_in[1];
    // d_in[2] = mask0, zeroed by reference -> ignored
    const float* Wq  = (const float*)d_in[3];
    const float* Wk  = (const float*)d_in[4];
    const float* Wv  = (const float*)d_in[5];
    const float* Wo  = (const float*)d_in[6];
    const float* Wr  = (const float*)d_in[7];
    const float* rwb = (const float*)d_in[8];
    const float* rrb = (const float*)d_in[9];
    const float* lnw = (const float*)d_in[10];
    const float* lnb = (const float*)d_in[11];
    float* out = (float*)d_out;

    char* ws = (char*)d_ws;
    unsigned short* qwb = (unsigned short*)(ws + 0);         // [48][1024][16] bf16
    unsigned short* qrb = (unsigned short*)(ws + 1572864);
    unsigned short* kh  = (unsigned short*)(ws + 3145728);
    unsigned short* vh  = (unsigned short*)(ws + 4718592);
    unsigned short* kr  = (unsigned short*)(ws + 6291456);   // [48][2048][16] bf16
    unsigned short* avb = (unsigned short*)(ws + 9437184);   // [4096][192] bf16
    unsigned short* xb  = (unsigned short*)(ws + 11010048);  // [4096][192] bf16
    unsigned short* rb  = (unsigned short*)(ws + 12582912);  // [8192][192] bf16
    unsigned short* WTq = (unsigned short*)(ws + 15728640);  // [192][192] bf16 (T)
    unsigned short* WTk = (unsigned short*)(ws + 15802368);
    unsigned short* WTv = (unsigned short*)(ws + 15876096);
    unsigned short* WTr = (unsigned short*)(ws + 15949824);
    unsigned short* Wob = (unsigned short*)(ws + 16023552);  // [192][192] bf16

    k_prep<<<dim3(9936), dim3(256), 0, stream>>>(x, r, Wq, Wk, Wv, Wr, Wo,
                                                 xb, rb, WTq, WTk, WTv, WTr, Wob);
    k_gemm_xr<<<dim3(3840), dim3(256), 0, stream>>>(xb, rb, WTq, WTk, WTv, WTr,
                                                    rwb, rrb, qwb, qrb, kh, vh, kr);
    k_attn_mfma<<<dim3(768), dim3(256), 0, stream>>>(qwb, qrb, kh, vh, kr, avb);
    k_out_ln<<<dim3(256), dim3(256), 0, stream>>>(avb, Wob, x, lnw, lnb, out);
}

// Round 7
// 64.846 us; speedup vs baseline: 3.9624x; 1.0843x over previous
//
#include <hip/hip_runtime.h>
#include <hip/hip_bf16.h>

// Sizes (compile-time)
#define SQ   1024      // S
#define BB   4         // B
#define DM   192       // D_MODEL
#define NH   12        // N_HEAD
#define DH   16        // D_HEAD
#define RL   2048      // RLEN
#define BN   (BB*NH)   // 48

typedef __attribute__((ext_vector_type(8))) short  short8;
typedef __attribute__((ext_vector_type(4))) float  f32x4;
typedef __attribute__((ext_vector_type(2))) unsigned u32x2;
typedef __attribute__((ext_vector_type(4))) unsigned u32x4;

__device__ __forceinline__ short f2bf(float f) {
    unsigned u = __float_as_uint(f);
    u += 0x7fff + ((u >> 16) & 1);
    return (short)(u >> 16);
}
// pack two f32 -> one u32 of 2 bf16 (lo, hi); compiler emits cvt_pk
__device__ __forceinline__ unsigned pkbf(float lo, float hi) {
    union { __hip_bfloat162 h; unsigned u; } cv;
    cv.h = __float22bfloat162_rn(make_float2(lo, hi));
    return cv.u;
}
__device__ __forceinline__ short8 as_s8(u32x4 v) {
    union { u32x4 u; short8 s; } c; c.u = v; return c.s;
}
#define P32SWAP(a, b) asm volatile("v_permlane32_swap_b32 %0, %1" : "+v"(a), "+v"(b))
#define P16SWAP(a, b) asm volatile("v_permlane16_swap_b32 %0, %1" : "+v"(a), "+v"(b))

// ---------- kernel P: bf16 conversions + weight transposes ----------
__global__ __launch_bounds__(256) void k_prep(
    const float* __restrict__ x, const float* __restrict__ r,
    const float* __restrict__ Wq, const float* __restrict__ Wk,
    const float* __restrict__ Wv, const float* __restrict__ Wr,
    const float* __restrict__ Wo,
    unsigned short* __restrict__ xb, unsigned short* __restrict__ rb,
    unsigned short* __restrict__ WTq, unsigned short* __restrict__ WTk,
    unsigned short* __restrict__ WTv, unsigned short* __restrict__ WTr,
    unsigned short* __restrict__ Wob)
{
    int idx = blockIdx.x * 256 + threadIdx.x;
    if (idx < 786432) { xb[idx] = (unsigned short)f2bf(x[idx]); return; }
    idx -= 786432;
    if (idx < 1572864) { rb[idx] = (unsigned short)f2bf(r[idx]); return; }
    idx -= 1572864;
    if (idx < 36864) { int nd = idx / 192, h = idx % 192;
                       WTq[idx] = (unsigned short)f2bf(Wq[h*192 + nd]); return; }
    idx -= 36864;
    if (idx < 36864) { int nd = idx / 192, h = idx % 192;
                       WTk[idx] = (unsigned short)f2bf(Wk[h*192 + nd]); return; }
    idx -= 36864;
    if (idx < 36864) { int nd = idx / 192, h = idx % 192;
                       WTv[idx] = (unsigned short)f2bf(Wv[h*192 + nd]); return; }
    idx -= 36864;
    if (idx < 36864) { int nd = idx / 192, h = idx % 192;
                       WTr[idx] = (unsigned short)f2bf(Wr[h*192 + nd]); return; }
    idx -= 36864;
    if (idx < 36864) { Wob[idx] = (unsigned short)f2bf(Wo[idx]); return; }
}

// ---------- kernel 1: fused x- and r-projections via MFMA, 2 row-tiles/wave ----------
// bid < 1152: x-path (128 row-pair-tiles x {Wq,Wk,Wv} x 3 col-chunks)
// else      : r-path (256 row-pair-tiles x 3 col-chunks)
__global__ __launch_bounds__(256) void k_gemm_xr(
    const unsigned short* __restrict__ xb, const unsigned short* __restrict__ rbm,
    const unsigned short* __restrict__ WTq, const unsigned short* __restrict__ WTk,
    const unsigned short* __restrict__ WTv, const unsigned short* __restrict__ WTr,
    const float* __restrict__ rwb, const float* __restrict__ rrb,
    unsigned short* __restrict__ qwb, unsigned short* __restrict__ qrb,
    unsigned short* __restrict__ kh, unsigned short* __restrict__ vh,
    unsigned short* __restrict__ kr)
{
    int bid = blockIdx.x;
    int tid = threadIdx.x, w = tid >> 6, lane = tid & 63, g = lane >> 4, mm = lane & 15;
    if (bid < 1152) {
        int rt2 = bid / 9, ch = bid % 9;
        int wsel = ch / 3, sub = ch % 3;
        int c0 = sub * 64 + w * 16;
        const unsigned short* WT = (wsel == 0) ? WTq : ((wsel == 1) ? WTk : WTv);
        const unsigned short* arow0 = xb + (size_t)(rt2*32 + mm) * 192 + 8*g;
        const unsigned short* arow1 = arow0 + 16*192;
        const unsigned short* brow = WT + (size_t)(c0 + mm) * 192 + 8*g;
        f32x4 acc0 = {0.f,0.f,0.f,0.f}, acc1 = {0.f,0.f,0.f,0.f};
        #pragma unroll
        for (int kk = 0; kk < 6; ++kk) {
            short8 b  = *(const short8*)(brow  + kk*32);
            short8 a0 = *(const short8*)(arow0 + kk*32);
            short8 a1 = *(const short8*)(arow1 + kk*32);
            acc0 = __builtin_amdgcn_mfma_f32_16x16x32_bf16(a0, b, acc0, 0, 0, 0);
            acc1 = __builtin_amdgcn_mfma_f32_16x16x32_bf16(a1, b, acc1, 0, 0, 0);
        }
        int col = c0 + mm, n = col >> 4, d = col & 15;
        if (wsel == 0) {
            const float SCL = 0.3606737602222409f;   // 0.25 * log2(e)
            float bw = rwb[col], br = rrb[col];
            #pragma unroll
            for (int r = 0; r < 4; ++r) {
                int row = rt2*32 + 4*g + r;
                int i = row >> 2, b2 = row & 3;
                size_t o = ((size_t)(b2*NH + n) * SQ + i) * DH + d;
                qwb[o] = (unsigned short)f2bf((acc0[r] + bw) * SCL);
                qrb[o] = (unsigned short)f2bf((acc0[r] + br) * SCL);
                int row1 = row + 16;
                int i1 = row1 >> 2, b21 = row1 & 3;
                size_t o1 = ((size_t)(b21*NH + n) * SQ + i1) * DH + d;
                qwb[o1] = (unsigned short)f2bf((acc1[r] + bw) * SCL);
                qrb[o1] = (unsigned short)f2bf((acc1[r] + br) * SCL);
            }
        } else {
            unsigned short* dst = (wsel == 1) ? kh : vh;
            #pragma unroll
            for (int r = 0; r < 4; ++r) {
                int row = rt2*32 + 4*g + r;
                int i = row >> 2, b2 = row & 3;
                dst[((size_t)(b2*NH + n) * SQ + i) * DH + d] = (unsigned short)f2bf(acc0[r]);
                int row1 = row + 16;
                int i1 = row1 >> 2, b21 = row1 & 3;
                dst[((size_t)(b21*NH + n) * SQ + i1) * DH + d] = (unsigned short)f2bf(acc1[r]);
            }
        }
    } else {
        int bb = bid - 1152;
        int rt2 = bb / 3, sub = bb % 3;
        int c0 = sub * 64 + w * 16;
        const unsigned short* arow0 = rbm + (size_t)(rt2*32 + mm) * 192 + 8*g;
        const unsigned short* arow1 = arow0 + 16*192;
        const unsigned short* brow = WTr + (size_t)(c0 + mm) * 192 + 8*g;
        f32x4 acc0 = {0.f,0.f,0.f,0.f}, acc1 = {0.f,0.f,0.f,0.f};
        #pragma unroll
        for (int kk = 0; kk < 6; ++kk) {
            short8 b  = *(const short8*)(brow  + kk*32);
            short8 a0 = *(const short8*)(arow0 + kk*32);
            short8 a1 = *(const short8*)(arow1 + kk*32);
            acc0 = __builtin_amdgcn_mfma_f32_16x16x32_bf16(a0, b, acc0, 0, 0, 0);
            acc1 = __builtin_amdgcn_mfma_f32_16x16x32_bf16(a1, b, acc1, 0, 0, 0);
        }
        int col = c0 + mm, n = col >> 4, d = col & 15;
        #pragma unroll
        for (int r = 0; r < 4; ++r) {
            int row = rt2*32 + 4*g + r;
            int j = row >> 2, b2 = row & 3;
            kr[((size_t)(b2*NH + n) * RL + j) * DH + d] = (unsigned short)f2bf(acc0[r]);
            int row1 = row + 16;
            int j1 = row1 >> 2, b21 = row1 & 3;
            kr[((size_t)(b21*NH + n) * RL + j1) * DH + d] = (unsigned short)f2bf(acc1[r]);
        }
    }
}

// ---------- kernel 2: swapped-layout MFMA flash attention with rel-shift ----------
// 4 waves / 64 queries of one head; KVBLK=64, 1 barrier per chunk.
// K and KR are consumed as A-fragments straight from global (L1/L2-resident),
// double-buffered in registers (T14). Only V (for the hw transpose read) and
// the per-wave BD band live in LDS. BD band layout [q][84] f32: b128 writes,
// b32 shifted reads, <=2-way conflicts.
__global__ __launch_bounds__(256, 3) void k_attn_mfma(
    const unsigned short* __restrict__ qwb, const unsigned short* __restrict__ qrb,
    const unsigned short* __restrict__ kh, const unsigned short* __restrict__ vh,
    const unsigned short* __restrict__ kr, unsigned short* __restrict__ av_b)
{
    __shared__ __align__(16) short vbuf[2][64*16];   // 4KB dbuf V
    __shared__ __align__(16) float bdls[4][16*84];   // 21.5KB per-wave BD band [q][c]

    int bid = blockIdx.x;
    int logical = (bid & 7) * 96 + (bid >> 3);  // XCD swizzle (768 % 8 == 0)
    int bn = logical >> 4;
    int i0b = (logical & 15) * 64;
    int tid = threadIdx.x, w = tid >> 6, lane = tid & 63;
    int g = lane >> 4, mm = lane & 15;
    size_t headK = (size_t)bn * SQ * DH;
    size_t headR = (size_t)bn * RL * DH;
    int koff = 8 * (g & 1);   // A-frag k-slice (junk for g>=2, multiplied by Q zeros)

    // Q fragments (B-operand: col=mm=query, k=8g+e; zero for g>=2)
    short8 qwf = {0,0,0,0,0,0,0,0}, qrf = {0,0,0,0,0,0,0,0};
    if (g < 2) {
        int qrow = i0b + 16*w + mm;
        qwf = *(const short8*)((const short*)qwb + headK + (size_t)qrow*DH + 8*g);
        qrf = *(const short8*)((const short*)qrb + headK + (size_t)qrow*DH + 8*g);
    }

    // ---- prologue: V0 -> LDS; K0/KR0 fragments -> regs ----
    if (tid < 128) {
        int rr2 = tid >> 1, hh = tid & 1;
        *(u32x4*)(&vbuf[0][rr2*16 + hh*8]) =
            *(const u32x4*)(vh + headK + (size_t)rr2*16 + hh*8);
    }
    const int basew0 = 1008 - i0b - 16*w;   // band base; m = basew0+64t+16tau+mm in [0,2047]
    u32x4 ka[4], krg[5], kan[4], krn[5];
    #pragma unroll
    for (int tp = 0; tp < 4; ++tp)
        ka[tp] = *(const u32x4*)(kh + headK + (size_t)(16*tp + mm)*16 + koff);
    #pragma unroll
    for (int tau = 0; tau < 5; ++tau)
        krg[tau] = *(const u32x4*)(kr + headR + (size_t)(basew0 + 16*tau + mm)*16 + koff);
    __syncthreads();

    float Lacc = 0.f;
    f32x4 opv = {0.f,0.f,0.f,0.f};
    float* bw_ = &bdls[w][0];
    const f32x4 z = {0.f,0.f,0.f,0.f};

    for (int t = 0; t < 16; ++t) {
        int cur = t & 1;
        // 1. issue next-chunk loads early (T14): K/KR frags + V stage regs
        u32x4 sva = {0,0,0,0}, svb = {0,0,0,0};
        bool ds = (t < 15);
        if (ds) {
            #pragma unroll
            for (int tp = 0; tp < 4; ++tp)
                kan[tp] = *(const u32x4*)(kh + headK + (size_t)(64*(t+1) + 16*tp + mm)*16 + koff);
            #pragma unroll
            for (int tau = 0; tau < 5; ++tau)
                krn[tau] = *(const u32x4*)(kr + headR + (size_t)(basew0 + 64*(t+1) + 16*tau + mm)*16 + koff);
            if (w == 1) {
                const unsigned short* p = vh + headK + (size_t)(64*(t+1) + lane)*16;
                sva = *(const u32x4*)p; svb = *(const u32x4*)(p + 8);
            }
        }

        // 2. BD band: 5 swapped MFMAs -> private LDS [q][84] (b128 writes)
        #pragma unroll
        for (int tau = 0; tau < 5; ++tau) {
            f32x4 bd = __builtin_amdgcn_mfma_f32_16x16x32_bf16(as_s8(krg[tau]), qrf, z, 0, 0, 0);
            *(f32x4*)(bw_ + mm*84 + 16*tau + 4*g) = bd;
        }

        // 3. AC (swapped) + shifted-BD add + exp2, all in C-layout
        unsigned pk[8]; float Lc = 0.f;
        #pragma unroll
        for (int tp = 0; tp < 4; ++tp) {
            f32x4 ac = __builtin_amdgcn_mfma_f32_16x16x32_bf16(as_s8(ka[tp]), qwf, z, 0, 0, 0);
            int cb = mm*84 + 16*tp + 4*g + 16 - mm;
            float p0 = __builtin_amdgcn_exp2f(ac[0] + bw_[cb + 0]);
            float p1 = __builtin_amdgcn_exp2f(ac[1] + bw_[cb + 1]);
            float p2 = __builtin_amdgcn_exp2f(ac[2] + bw_[cb + 2]);
            float p3 = __builtin_amdgcn_exp2f(ac[3] + bw_[cb + 3]);
            Lc += (p0 + p1) + (p2 + p3);
            pk[2*tp]     = pkbf(p0, p1);
            pk[2*tp + 1] = pkbf(p2, p3);
        }
        Lacc += Lc;

        // 4. C-layout P -> PV B-frag via permlane swaps (in-register transpose)
        P32SWAP(pk[0], pk[2]); P16SWAP(pk[0], pk[2]);
        P32SWAP(pk[1], pk[3]); P16SWAP(pk[1], pk[3]);
        P32SWAP(pk[4], pk[6]); P16SWAP(pk[4], pk[6]);
        P32SWAP(pk[5], pk[7]); P16SWAP(pk[5], pk[7]);

        // 5. PV: V A-frags via hw transpose-read, 2 MFMAs (keys 0-31, 32-63)
        unsigned vb0 = (unsigned)(size_t)(&vbuf[cur][0])
                     + ((unsigned)mm << 3) + ((unsigned)g << 8);
        {
            u32x2 t0, t1;
            asm volatile("ds_read_b64_tr_b16 %0, %2 offset:0\n\t"
                         "ds_read_b64_tr_b16 %1, %2 offset:128\n\t"
                         "s_waitcnt lgkmcnt(0)"
                         : "=&v"(t0), "=&v"(t1) : "v"(vb0));
            __builtin_amdgcn_sched_barrier(0);
            union { unsigned u[4]; short8 s; } va, pb;
            va.u[0]=t0[0]; va.u[1]=t0[1]; va.u[2]=t1[0]; va.u[3]=t1[1];
            pb.u[0]=pk[0]; pb.u[1]=pk[1]; pb.u[2]=pk[2]; pb.u[3]=pk[3];
            opv = __builtin_amdgcn_mfma_f32_16x16x32_bf16(va.s, pb.s, opv, 0, 0, 0);
        }
        {
            u32x2 t0, t1;
            asm volatile("ds_read_b64_tr_b16 %0, %2 offset:0\n\t"
                         "ds_read_b64_tr_b16 %1, %2 offset:128\n\t"
                         "s_waitcnt lgkmcnt(0)"
                         : "=&v"(t0), "=&v"(t1) : "v"(vb0 + 1024));
            __builtin_amdgcn_sched_barrier(0);
            union { unsigned u[4]; short8 s; } va, pb;
            va.u[0]=t0[0]; va.u[1]=t0[1]; va.u[2]=t1[0]; va.u[3]=t1[1];
            pb.u[0]=pk[4]; pb.u[1]=pk[5]; pb.u[2]=pk[6]; pb.u[3]=pk[7];
            opv = __builtin_amdgcn_mfma_f32_16x16x32_bf16(va.s, pb.s, opv, 0, 0, 0);
        }

        // 6. V stage-write (wave 1 only, other buffer) + single barrier
        if (ds) {
            if (w == 1) {
                *(u32x4*)(&vbuf[cur^1][lane*16])     = sva;
                *(u32x4*)(&vbuf[cur^1][lane*16 + 8]) = svb;
            }
        }
        __syncthreads();
        if (ds) {
            #pragma unroll
            for (int tp = 0; tp < 4; ++tp) ka[tp] = kan[tp];
            #pragma unroll
            for (int tau = 0; tau < 5; ++tau) krg[tau] = krn[tau];
        }
    }

    // ---- epilogue: L is lane-local per query; reduce across g, store bf16 ----
    Lacc += __shfl_xor(Lacc, 16);
    Lacc += __shfl_xor(Lacc, 32);
    float inv = 1.0f / Lacc;
    int b2 = bn / NH, nn = bn % NH;
    int i = i0b + 16*w + mm;
    unsigned o0 = pkbf(opv[0]*inv, opv[1]*inv);
    unsigned o1 = pkbf(opv[2]*inv, opv[3]*inv);
    u32x2 ov = {o0, o1};
    *(u32x2*)(av_b + ((size_t)i*4 + b2)*192 + nn*16 + 4*g) = ov;
}

// ---------- kernel 3: output projection + residual + LayerNorm (fused) ----------
// grid 256: block computes 16 rows x all 192 cols (wave w -> col-tiles w*48+{0,16,32}),
// stores to LDS, then LN in-block (16 rows x 16 threads each).
__global__ __launch_bounds__(256) void k_out_ln(
    const unsigned short* __restrict__ avb, const unsigned short* __restrict__ Wob,
    const float* __restrict__ x,
    const float* __restrict__ lnw, const float* __restrict__ lnb,
    float* __restrict__ out)
{
    __shared__ __align__(16) float os[16][196];
    int tid = threadIdx.x, w = tid >> 6, lane = tid & 63, g = lane >> 4, mm = lane & 15;
    int rt = blockIdx.x;
    const unsigned short* arow = avb + (size_t)(rt*16 + mm)*192 + 8*g;
    short8 a[6];
    #pragma unroll
    for (int kk = 0; kk < 6; ++kk) a[kk] = *(const short8*)(arow + kk*32);
    #pragma unroll
    for (int s = 0; s < 3; ++s) {
        int c0 = w*48 + s*16;
        const unsigned short* brow = Wob + (size_t)(c0 + mm)*192 + 8*g;
        f32x4 acc = {0.f,0.f,0.f,0.f};
        #pragma unroll
        for (int kk = 0; kk < 6; ++kk) {
            short8 b = *(const short8*)(brow + kk*32);
            acc = __builtin_amdgcn_mfma_f32_16x16x32_bf16(a[kk], b, acc, 0, 0, 0);
        }
        int col = c0 + mm;
        #pragma unroll
        for (int r = 0; r < 4; ++r) {
            int rl = 4*g + r;
            os[rl][col] = acc[r] + x[(size_t)(rt*16 + rl)*192 + col];
        }
    }
    __syncthreads();
    int row = tid >> 4, seg = tid & 15;
    const float* ors = &os[row][0] + seg*12;
    f32x4 v0 = *(const f32x4*)(ors);
    f32x4 v1 = *(const f32x4*)(ors + 4);
    f32x4 v2 = *(const f32x4*)(ors + 8);
    float s1 = ((v0[0]+v0[1])+(v0[2]+v0[3])) + ((v1[0]+v1[1])+(v1[2]+v1[3]))
             + ((v2[0]+v2[1])+(v2[2]+v2[3]));
    float q1 = ((v0[0]*v0[0]+v0[1]*v0[1])+(v0[2]*v0[2]+v0[3]*v0[3]))
             + ((v1[0]*v1[0]+v1[1]*v1[1])+(v1[2]*v1[2]+v1[3]*v1[3]))
             + ((v2[0]*v2[0]+v2[1]*v2[1])+(v2[2]*v2[2]+v2[3]*v2[3]));
    #pragma unroll
    for (int off = 1; off < 16; off <<= 1) {
        s1 += __shfl_xor(s1, off);
        q1 += __shfl_xor(q1, off);
    }
    float mean = s1 * (1.0f / 192.0f);
    float var  = q1 * (1.0f / 192.0f) - mean * mean;
    float rstd = rsqrtf(var + 1e-12f);
    int c0 = seg * 12;
    size_t ro = (size_t)(rt*16 + row) * 192;
    #pragma unroll
    for (int c = 0; c < 12; ++c) {
        float v = (c < 4) ? v0[c] : ((c < 8) ? v1[c-4] : v2[c-8]);
        out[ro + c0 + c] = (v - mean) * rstd * lnw[c0 + c] + lnb[c0 + c];
    }
}

extern "C" void kernel_launch(void* const* d_in, const int* in_sizes, int n_in,
                              void* d_out, int out_size, void* d_ws, size_t ws_size,
                              hipStream_t stream) {
    const float* x   = (const float*)d_in[0];
    const float* r   = (const float*)d_in[1];
    // d_in[2] = mask0, zeroed by reference -> ignored
    const float* Wq  = (const float*)d_in[3];
    const float* Wk  = (const float*)d_in[4];
    const float* Wv  = (const float*)d_in[5];
    const float* Wo  = (const float*)d_in[6];
    const float* Wr  = (const float*)d_in[7];
    const float* rwb = (const float*)d_in[8];
    const float* rrb = (const float*)d_in[9];
    const float* lnw = (const float*)d_in[10];
    const float* lnb = (const float*)d_in[11];
    float* out = (float*)d_out;

    char* ws = (char*)d_ws;
    unsigned short* qwb = (unsigned short*)(ws + 0);         // [48][1024][16] bf16
    unsigned short* qrb = (unsigned short*)(ws + 1572864);
    unsigned short* kh  = (unsigned short*)(ws + 3145728);
    unsigned short* vh  = (unsigned short*)(ws + 4718592);
    unsigned short* kr  = (unsigned short*)(ws + 6291456);   // [48][2048][16] bf16
    unsigned short* avb = (unsigned short*)(ws + 9437184);   // [4096][192] bf16
    unsigned short* xb  = (unsigned short*)(ws + 11010048);  // [4096][192] bf16
    unsigned short* rb  = (unsigned short*)(ws + 12582912);  // [8192][192] bf16
    unsigned short* WTq = (unsigned short*)(ws + 15728640);  // [192][192] bf16 (T)
    unsigned short* WTk = (unsigned short*)(ws + 15802368);
    unsigned short* WTv = (unsigned short*)(ws + 15876096);
    unsigned short* WTr = (unsigned short*)(ws + 15949824);
    unsigned short* Wob = (unsigned short*)(ws + 16023552);  // [192][192] bf16

    k_prep<<<dim3(9936), dim3(256), 0, stream>>>(x, r, Wq, Wk, Wv, Wr, Wo,
                                                 xb, rb, WTq, WTk, WTv, WTr, Wob);
    k_gemm_xr<<<dim3(1920), dim3(256), 0, stream>>>(xb, rb, WTq, WTk, WTv, WTr,
                                                    rwb, rrb, qwb, qrb, kh, vh, kr);
    k_attn_mfma<<<dim3(768), dim3(256), 0, stream>>>(qwb, qrb, kh, vh, kr, avb);
    k_out_ln<<<dim3(256), dim3(256), 0, stream>>>(avb, Wob, x, lnw, lnb, out);
}